// Round 2
// baseline (199.836 us; speedup 1.0000x reference)
//
#include <hip/hip_runtime.h>
#include <hip/hip_bf16.h>

#define N_  2
#define C_  256
#define CK_ 32
#define L_  4096

typedef __attribute__((ext_vector_type(8))) short short8;   // 8 bf16 (4 VGPRs)
typedef __attribute__((ext_vector_type(4))) float f32x4;    // MFMA C/D
typedef __attribute__((ext_vector_type(2))) unsigned int uint2v;
typedef unsigned short ushort;

__device__ __forceinline__ ushort f2bf(float f){
  unsigned u = __float_as_uint(f);
  u += 0x7fffu + ((u >> 16) & 1u);     // RNE
  return (ushort)(u >> 16);
}

__device__ __forceinline__ f32x4 mfma16(short8 a, short8 b, f32x4 c){
  return __builtin_amdgcn_mfma_f32_16x16x32_bf16(a, b, c, 0, 0, 0);
}

// ---------- convert+transpose x: [n][C][L] f32 -> [n][L][C] bf16 ----------
__global__ __launch_bounds__(256) void convert_x_kernel(
    const float* __restrict__ x1, const float* __restrict__ x2,
    ushort* __restrict__ xT1, ushort* __restrict__ xT2){
  __shared__ float tt[64][130];        // [l][c]
  int z = blockIdx.z; int n = z & 1;
  const float* x = (z >> 1) ? x2 : x1;
  ushort* xT = (z >> 1) ? xT2 : xT1;
  int l0 = blockIdx.x * 64, c0 = blockIdx.y * 128;
  int t = threadIdx.x;
  const float* xs = x + (size_t)n * C_ * L_;
  ushort* xd = xT + (size_t)n * L_ * C_;
  int lq = (t & 15) * 4, cl = t >> 4;              // cl 0..15
#pragma unroll
  for (int r = 0; r < 8; ++r){
    int c = r * 16 + cl;
    float4 f = *(const float4*)(xs + (size_t)(c0 + c) * L_ + l0 + lq);
    tt[lq + 0][c] = f.x; tt[lq + 1][c] = f.y; tt[lq + 2][c] = f.z; tt[lq + 3][c] = f.w;
  }
  __syncthreads();
  int c8 = (t & 15) * 8, ll = t >> 4;              // ll 0..15
#pragma unroll
  for (int r = 0; r < 4; ++r){
    int l = r * 16 + ll;
    union { ushort u[8]; short8 v; } pk;
#pragma unroll
    for (int j = 0; j < 8; ++j) pk.u[j] = f2bf(tt[l][c8 + j]);
    *(short8*)(xd + (size_t)(l0 + l) * C_ + c0 + c8) = pk.v;
  }
}

// ---------- convert weights f32 -> bf16 (flat) ----------
__global__ __launch_bounds__(256) void convert_w_kernel(
    const float* __restrict__ Wk1, const float* __restrict__ Wk2,
    const float* __restrict__ Wv1, const float* __restrict__ Wv2,
    ushort* __restrict__ o1, ushort* __restrict__ o2,
    ushort* __restrict__ o3, ushort* __restrict__ o4){
  int idx = blockIdx.x * 256 + threadIdx.x;
  const int KS = CK_ * C_;      // 8192
  const int VS = C_ * C_;       // 65536
  if (idx < KS)                 o1[idx] = f2bf(Wk1[idx]);
  else if (idx < 2*KS)          o2[idx - KS] = f2bf(Wk2[idx - KS]);
  else if (idx < 2*KS + VS)     o3[idx - 2*KS] = f2bf(Wv1[idx - 2*KS]);
  else if (idx < 2*KS + 2*VS)   o4[idx - 2*KS - VS] = f2bf(Wv2[idx - 2*KS - VS]);
}

// ---------- fused projections: k1t/k2t [n][L][CK], v1/v2 [n][C][L] ----------
__global__ __launch_bounds__(256) void proj_kernel(
    const ushort* __restrict__ xT1, const ushort* __restrict__ xT2,
    const ushort* __restrict__ Wk1b, const ushort* __restrict__ Wk2b,
    const ushort* __restrict__ Wv1b, const ushort* __restrict__ Wv2b,
    const float* __restrict__ bk1, const float* __restrict__ bk2,
    const float* __restrict__ bv1, const float* __restrict__ bv2,
    ushort* __restrict__ k1t, ushort* __restrict__ k2t,
    ushort* __restrict__ v1,  ushort* __restrict__ v2){
  int y = blockIdx.y, n = blockIdx.z;
  int t = threadIdx.x, w = t >> 6, lane = t & 63, quad = lane >> 4, low = lane & 15;
  const ushort* X; const ushort* W; const float* bias; ushort* outp; int jt; bool isK;
  if (y < 8)       { X = xT1; W = Wv1b; bias = bv1; outp = v1;  jt = y;     isK = false; }
  else if (y < 16) { X = xT2; W = Wv2b; bias = bv2; outp = v2;  jt = y - 8; isK = false; }
  else if (y == 16){ X = xT1; W = Wk1b; bias = bk1; outp = k1t; jt = 0;     isK = true; }
  else             { X = xT2; W = Wk2b; bias = bk2; outp = k2t; jt = 0;     isK = true; }
  int j0 = jt * 32;
  int l0 = blockIdx.x * 128 + w * 32;
  const ushort* Xn = X + (size_t)n * L_ * C_;
  f32x4 acc[2][2] = {};
#pragma unroll
  for (int kc = 0; kc < 8; ++kc){
    short8 a[2], b[2];
#pragma unroll
    for (int js = 0; js < 2; ++js)
      a[js] = *(const short8*)(W + (size_t)(j0 + js*16 + low)*C_ + kc*32 + quad*8);
#pragma unroll
    for (int ls = 0; ls < 2; ++ls)
      b[ls] = *(const short8*)(Xn + (size_t)(l0 + ls*16 + low)*C_ + kc*32 + quad*8);
#pragma unroll
    for (int js = 0; js < 2; ++js)
#pragma unroll
      for (int ls = 0; ls < 2; ++ls)
        acc[js][ls] = mfma16(a[js], b[ls], acc[js][ls]);
  }
#pragma unroll
  for (int js = 0; js < 2; ++js){
    f32x4 bb = *(const f32x4*)(bias + j0 + js*16 + quad*4);
#pragma unroll
    for (int ls = 0; ls < 2; ++ls){
      int l = l0 + ls*16 + low;
      if (!isK){
#pragma unroll
        for (int r = 0; r < 4; ++r){
          int j = j0 + js*16 + quad*4 + r;
          outp[((size_t)n*C_ + j)*L_ + l] = f2bf(acc[js][ls][r] + bb[r]);
        }
      } else {
        union { ushort u[4]; uint2v v; } pk;
#pragma unroll
        for (int r = 0; r < 4; ++r) pk.u[r] = f2bf(acc[js][ls][r] + bb[r]);
        *(uint2v*)(outp + ((size_t)n*L_ + l)*CK_ + j0 + js*16 + quad*4) = pk.v;
      }
    }
  }
}

// ---------- stats: partial row/col sums of exp(cor) ----------
__global__ __launch_bounds__(256) void stats_kernel(
    const ushort* __restrict__ k1t, const ushort* __restrict__ k2t,
    float* __restrict__ S1part, float* __restrict__ S2part){
  int n = blockIdx.z;
  int m0 = blockIdx.x * 128, l0 = blockIdx.y * 128;
  int t = threadIdx.x, w = t >> 6, lane = t & 63, quad = lane >> 4, low = lane & 15;
  __shared__ float rowsum[128];
  __shared__ float colsum[4][128];
  const ushort* ka = k1t + (size_t)n * L_ * CK_;
  const ushort* kb = k2t + (size_t)n * L_ * CK_;
  short8 a[2], b[8];
#pragma unroll
  for (int lt = 0; lt < 2; ++lt)
    a[lt] = *(const short8*)(ka + (size_t)(l0 + w*32 + lt*16 + low)*CK_ + quad*8);
#pragma unroll
  for (int mt = 0; mt < 8; ++mt)
    b[mt] = *(const short8*)(kb + (size_t)(m0 + mt*16 + low)*CK_ + quad*8);
  float rp[2][4] = {}; float cp[8] = {};
  const f32x4 zero = {0.f, 0.f, 0.f, 0.f};
#pragma unroll
  for (int lt = 0; lt < 2; ++lt)
#pragma unroll
    for (int mt = 0; mt < 8; ++mt){
      f32x4 e = mfma16(a[lt], b[mt], zero);
#pragma unroll
      for (int r = 0; r < 4; ++r){
        float v = __builtin_amdgcn_exp2f(e[r] * 1.44269504088896f);
        rp[lt][r] += v;
        cp[mt] += v;
      }
    }
#pragma unroll
  for (int lt = 0; lt < 2; ++lt)
#pragma unroll
    for (int r = 0; r < 4; ++r){
      float v = rp[lt][r];
      v += __shfl_xor(v, 1); v += __shfl_xor(v, 2);
      v += __shfl_xor(v, 4); v += __shfl_xor(v, 8);
      if (low == 0) rowsum[w*32 + lt*16 + quad*4 + r] = v;
    }
#pragma unroll
  for (int mt = 0; mt < 8; ++mt){
    float v = cp[mt];
    v += __shfl_xor(v, 16); v += __shfl_xor(v, 32);
    if (quad == 0) colsum[w][mt*16 + low] = v;
  }
  __syncthreads();
  if (t < 128)
    S1part[((size_t)n*32 + blockIdx.x)*L_ + l0 + t] = rowsum[t];
  else {
    int m = t - 128;
    S2part[((size_t)n*32 + blockIdx.y)*L_ + m0 + m] =
        colsum[0][m] + colsum[1][m] + colsum[2][m] + colsum[3][m];
  }
}

// ---------- reduce partials -> lsv = log2(1/S) = -log2(S) ----------
// (r-kernel computes P = exp2(cor*log2e + lsv) = exp(cor)/S)
__global__ __launch_bounds__(256) void reduce_inv_kernel(
    const float* __restrict__ S1part, const float* __restrict__ S2part,
    float* __restrict__ invS1, float* __restrict__ invS2){
  int idx = blockIdx.x * 256 + threadIdx.x;          // 0..16383
  int which = idx >> 13;
  int r = idx & 8191;                                // n*L + l
  int n = r >> 12, l = r & 4095;
  const float* P = which ? S2part : S1part;
  float s = 0.f;
#pragma unroll
  for (int j = 0; j < 32; ++j) s += P[((size_t)n*32 + j)*L_ + l];
  (which ? invS2 : invS1)[(size_t)n*L_ + l] = -__builtin_amdgcn_logf(s);
}

#define LOG2E_ 1.44269504088896f

// ---------- unified flash r-kernel v5: in-register P, ZERO main-loop barriers
// Key trick: the e-MFMA's A operand rows are loaded PERMUTED — A-row m comes
// from kA row p + (m>>2)*8 + (m&3) (and +4 for the second e-MFMA). The C/D
// fragment layout (row = quad*4+r, col = low) then lands EXACTLY in the
// B-fragment layout the PV MFMA needs (k = quad*8+j, n = low): lane
// (quad,low) holds P[p+quad*8 .. p+quad*8+7][q=low] after exp+bf16 pack.
// So P never touches LDS and the main loop has no __syncthreads at all
// (v4 paid 2 barriers + an LDS round-trip + 6.3M bank-conflict cycles per
// dispatch for this transpose). Each wave owns a disjoint 32-row p-slice
// per 128-chunk and contracts the FULL 128-c block over it (acc = 128
// VGPR/lane); the 4 per-wave partial accumulators are summed in a short
// LDS epilogue (17 KB, 16 barriers total).
__global__ __launch_bounds__(256, 2) void cross_attn_r_kernel(
    const ushort* __restrict__ k1t, const ushort* __restrict__ k2t,
    const ushort* __restrict__ v1,  const ushort* __restrict__ v2,
    const float* __restrict__ invS1, const float* __restrict__ invS2,
    const float* __restrict__ x1, const float* __restrict__ x2,
    float* __restrict__ out){
  int z = blockIdx.z; int which = z >> 1; int n = z & 1;
  const ushort* kA = which ? k2t : k1t;
  const ushort* kB = which ? k1t : k2t;
  const ushort* V  = which ? v2  : v1;
  const float* iS  = which ? invS2 : invS1;
  const float* X   = which ? x2 : x1;
  float* O = out + (size_t)which * N_ * C_ * L_;
  int q0 = blockIdx.x * 64, c0 = blockIdx.y * 128;
  int t = threadIdx.x, w = t >> 6, lane = t & 63, quad = lane >> 4, low = lane & 15;
  __shared__ __align__(16) float red[4][16][68];   // [wave][c_local][q(+pad)]
  const ushort* kAn = kA + (size_t)n * L_ * CK_;
  const ushort* kBn = kB + (size_t)n * L_ * CK_;
  const ushort* Vn  = V  + (size_t)n * C_ * L_;
  const float*  iSn = iS + (size_t)n * L_;

  // permuted-row A base: A-row m=low -> kA row (m>>2)*8 + (m&3)
  const ushort* kA_base = kAn + (size_t)((low >> 2) * 8 + (low & 3)) * CK_ + quad * 8;
  const float*  sv_base = iSn + quad * 8;
  const ushort* V_base  = Vn + (size_t)(c0 + low) * L_ + quad * 8;

  // E-phase B operand (q rows of kB) is loop-invariant: preload once.
  short8 be[4];
#pragma unroll
  for (int qs = 0; qs < 4; ++qs)
    be[qs] = *(const short8*)(kBn + (size_t)(q0 + qs*16 + low) * CK_ + quad * 8);

  f32x4 acc[8][4] = {};
  const f32x4 zero = {0.f, 0.f, 0.f, 0.f};

  // software-pipelined kA-row + scale loads (16 VGPR)
  int pfirst = w * 32;
  short8 a0 = *(const short8*)(kA_base + (size_t)pfirst * CK_);
  short8 a1 = *(const short8*)(kA_base + (size_t)(pfirst + 4) * CK_);
  f32x4 sv0 = *(const f32x4*)(sv_base + pfirst);
  f32x4 sv1 = *(const f32x4*)(sv_base + pfirst + 4);

  for (int kk = 0; kk < L_ / 128; ++kk){
    int p = kk * 128 + w * 32;
    // V for this iteration: issued first, consumed after e-phase (~330 cyc)
    short8 vv[8];
#pragma unroll
    for (int ct = 0; ct < 8; ++ct)
      vv[ct] = *(const short8*)(V_base + (size_t)ct * 16 * L_ + p);
    // e-phase: P rows p..p+31 (this wave's slice), cols q0..q0+63, in-register
    short8 pb[4];
#pragma unroll
    for (int qs = 0; qs < 4; ++qs){
      f32x4 e0 = mfma16(a0, be[qs], zero);   // rows p+quad*8+r
      f32x4 e1 = mfma16(a1, be[qs], zero);   // rows p+quad*8+4+r
      union { ushort u[8]; short8 v; } pk;
#pragma unroll
      for (int r = 0; r < 4; ++r)
        pk.u[r]     = f2bf(__builtin_amdgcn_exp2f(__fmaf_rn(e0[r], LOG2E_, sv0[r])));
#pragma unroll
      for (int r = 0; r < 4; ++r)
        pk.u[4 + r] = f2bf(__builtin_amdgcn_exp2f(__fmaf_rn(e1[r], LOG2E_, sv1[r])));
      pb[qs] = pk.v;
    }
    // prefetch next iteration's kA rows + scales (hidden under PV MFMAs)
    int pn = ((kk + 1) & 31) * 128 + w * 32;   // wraps on last iter (harmless)
    a0 = *(const short8*)(kA_base + (size_t)pn * CK_);
    a1 = *(const short8*)(kA_base + (size_t)(pn + 4) * CK_);
    sv0 = *(const f32x4*)(sv_base + pn);
    sv1 = *(const f32x4*)(sv_base + pn + 4);
    // PV: acc[c-tile][q-tile] += V[c, p-slice] * P[p-slice, q]
#pragma unroll
    for (int ct = 0; ct < 8; ++ct)
#pragma unroll
      for (int qs = 0; qs < 4; ++qs)
        acc[ct][qs] = mfma16(vv[ct], pb[qs], acc[ct][qs]);
  }

  // --- epilogue: cross-wave reduction of the 4 disjoint-p partials + x add
  int cl = t >> 4, qg = (t & 15) * 4;
#pragma unroll
  for (int ct = 0; ct < 8; ++ct){
#pragma unroll
    for (int qs = 0; qs < 4; ++qs)
#pragma unroll
      for (int r = 0; r < 4; ++r)
        red[w][quad*4 + r][qs*16 + low] = acc[ct][qs][r];
    __syncthreads();
    f32x4 s0 = *(const f32x4*)&red[0][cl][qg];
    f32x4 s1 = *(const f32x4*)&red[1][cl][qg];
    f32x4 s2 = *(const f32x4*)&red[2][cl][qg];
    f32x4 s3 = *(const f32x4*)&red[3][cl][qg];
    f32x4 s = (s0 + s1) + (s2 + s3);
    size_t idx = ((size_t)n * C_ + c0 + ct*16 + cl) * L_ + q0 + qg;
    const float4 xv = *(const float4*)(X + idx);
    float4 o = make_float4(xv.x + s[0], xv.y + s[1], xv.z + s[2], xv.w + s[3]);
    *(float4*)(O + idx) = o;
    __syncthreads();
  }
}

extern "C" void kernel_launch(void* const* d_in, const int* in_sizes, int n_in,
                              void* d_out, int out_size, void* d_ws, size_t ws_size,
                              hipStream_t stream) {
  const float* x1  = (const float*)d_in[0];
  const float* x2  = (const float*)d_in[1];
  const float* Wk1 = (const float*)d_in[2];
  const float* bk1 = (const float*)d_in[3];
  const float* Wk2 = (const float*)d_in[4];
  const float* bk2 = (const float*)d_in[5];
  const float* Wv1 = (const float*)d_in[6];
  const float* bv1 = (const float*)d_in[7];
  const float* Wv2 = (const float*)d_in[8];
  const float* bv2 = (const float*)d_in[9];

  char* ws = (char*)d_ws;
  size_t off = 0;
  auto carve = [&](size_t bytes) -> void* {
    void* p = ws + off; off += (bytes + 255) & ~(size_t)255; return p;
  };
  ushort* xT1   = (ushort*)carve((size_t)N_*L_*C_*2);
  ushort* xT2   = (ushort*)carve((size_t)N_*L_*C_*2);
  ushort* Wk1b  = (ushort*)carve((size_t)CK_*C_*2);
  ushort* Wk2b  = (ushort*)carve((size_t)CK_*C_*2);
  ushort* Wv1b  = (ushort*)carve((size_t)C_*C_*2);
  ushort* Wv2b  = (ushort*)carve((size_t)C_*C_*2);
  ushort* k1t   = (ushort*)carve((size_t)N_*L_*CK_*2);
  ushort* k2t   = (ushort*)carve((size_t)N_*L_*CK_*2);
  ushort* v1    = (ushort*)carve((size_t)N_*C_*L_*2);
  ushort* v2    = (ushort*)carve((size_t)N_*C_*L_*2);
  float*  S1p   = (float*)carve((size_t)N_*32*L_*4);
  float*  S2p   = (float*)carve((size_t)N_*32*L_*4);
  float*  invS1 = (float*)carve((size_t)N_*L_*4);
  float*  invS2 = (float*)carve((size_t)N_*L_*4);

  convert_x_kernel<<<dim3(L_/64, C_/128, 4), 256, 0, stream>>>(x1, x2, xT1, xT2);
  convert_w_kernel<<<dim3((2*CK_*C_ + 2*C_*C_) / 256), 256, 0, stream>>>(
      Wk1, Wk2, Wv1, Wv2, Wk1b, Wk2b, Wv1b, Wv2b);
  proj_kernel<<<dim3(L_/128, 18, N_), 256, 0, stream>>>(
      xT1, xT2, Wk1b, Wk2b, Wv1b, Wv2b, bk1, bk2, bv1, bv2, k1t, k2t, v1, v2);
  stats_kernel<<<dim3(L_/128, L_/128, N_), 256, 0, stream>>>(k1t, k2t, S1p, S2p);
  reduce_inv_kernel<<<dim3(2*N_*L_/256), 256, 0, stream>>>(S1p, S2p, invS1, invS2);
  cross_attn_r_kernel<<<dim3(L_/64, C_/128, 2*N_), 256, 0, stream>>>(
      k1t, k2t, v1, v2, invS1, invS2, x1, x2, (float*)d_out);
}

// Round 3
// 199.491 us; speedup vs baseline: 1.0017x; 1.0017x over previous
//
#include <hip/hip_runtime.h>
#include <hip/hip_bf16.h>

#define N_  2
#define C_  256
#define CK_ 32
#define L_  4096

typedef __attribute__((ext_vector_type(8))) short short8;   // 8 bf16 (4 VGPRs)
typedef __attribute__((ext_vector_type(4))) float f32x4;    // MFMA C/D
typedef __attribute__((ext_vector_type(2))) unsigned int uint2v;
typedef unsigned short ushort;

__device__ __forceinline__ ushort f2bf(float f){
  unsigned u = __float_as_uint(f);
  u += 0x7fffu + ((u >> 16) & 1u);     // RNE
  return (ushort)(u >> 16);
}

__device__ __forceinline__ f32x4 mfma16(short8 a, short8 b, f32x4 c){
  return __builtin_amdgcn_mfma_f32_16x16x32_bf16(a, b, c, 0, 0, 0);
}

// ---------- convert+transpose x: [n][C][L] f32 -> [n][L][C] bf16 ----------
__global__ __launch_bounds__(256) void convert_x_kernel(
    const float* __restrict__ x1, const float* __restrict__ x2,
    ushort* __restrict__ xT1, ushort* __restrict__ xT2){
  __shared__ float tt[64][130];        // [l][c]
  int z = blockIdx.z; int n = z & 1;
  const float* x = (z >> 1) ? x2 : x1;
  ushort* xT = (z >> 1) ? xT2 : xT1;
  int l0 = blockIdx.x * 64, c0 = blockIdx.y * 128;
  int t = threadIdx.x;
  const float* xs = x + (size_t)n * C_ * L_;
  ushort* xd = xT + (size_t)n * L_ * C_;
  int lq = (t & 15) * 4, cl = t >> 4;              // cl 0..15
#pragma unroll
  for (int r = 0; r < 8; ++r){
    int c = r * 16 + cl;
    float4 f = *(const float4*)(xs + (size_t)(c0 + c) * L_ + l0 + lq);
    tt[lq + 0][c] = f.x; tt[lq + 1][c] = f.y; tt[lq + 2][c] = f.z; tt[lq + 3][c] = f.w;
  }
  __syncthreads();
  int c8 = (t & 15) * 8, ll = t >> 4;              // ll 0..15
#pragma unroll
  for (int r = 0; r < 4; ++r){
    int l = r * 16 + ll;
    union { ushort u[8]; short8 v; } pk;
#pragma unroll
    for (int j = 0; j < 8; ++j) pk.u[j] = f2bf(tt[l][c8 + j]);
    *(short8*)(xd + (size_t)(l0 + l) * C_ + c0 + c8) = pk.v;
  }
}

// ---------- convert weights f32 -> bf16 (flat) ----------
__global__ __launch_bounds__(256) void convert_w_kernel(
    const float* __restrict__ Wk1, const float* __restrict__ Wk2,
    const float* __restrict__ Wv1, const float* __restrict__ Wv2,
    ushort* __restrict__ o1, ushort* __restrict__ o2,
    ushort* __restrict__ o3, ushort* __restrict__ o4){
  int idx = blockIdx.x * 256 + threadIdx.x;
  const int KS = CK_ * C_;      // 8192
  const int VS = C_ * C_;       // 65536
  if (idx < KS)                 o1[idx] = f2bf(Wk1[idx]);
  else if (idx < 2*KS)          o2[idx - KS] = f2bf(Wk2[idx - KS]);
  else if (idx < 2*KS + VS)     o3[idx - 2*KS] = f2bf(Wv1[idx - 2*KS]);
  else if (idx < 2*KS + 2*VS)   o4[idx - 2*KS - VS] = f2bf(Wv2[idx - 2*KS - VS]);
}

// ---------- fused projections: k1t/k2t [n][L][CK], v1/v2 [n][C][L] ----------
__global__ __launch_bounds__(256) void proj_kernel(
    const ushort* __restrict__ xT1, const ushort* __restrict__ xT2,
    const ushort* __restrict__ Wk1b, const ushort* __restrict__ Wk2b,
    const ushort* __restrict__ Wv1b, const ushort* __restrict__ Wv2b,
    const float* __restrict__ bk1, const float* __restrict__ bk2,
    const float* __restrict__ bv1, const float* __restrict__ bv2,
    ushort* __restrict__ k1t, ushort* __restrict__ k2t,
    ushort* __restrict__ v1,  ushort* __restrict__ v2){
  int y = blockIdx.y, n = blockIdx.z;
  int t = threadIdx.x, w = t >> 6, lane = t & 63, quad = lane >> 4, low = lane & 15;
  const ushort* X; const ushort* W; const float* bias; ushort* outp; int jt; bool isK;
  if (y < 8)       { X = xT1; W = Wv1b; bias = bv1; outp = v1;  jt = y;     isK = false; }
  else if (y < 16) { X = xT2; W = Wv2b; bias = bv2; outp = v2;  jt = y - 8; isK = false; }
  else if (y == 16){ X = xT1; W = Wk1b; bias = bk1; outp = k1t; jt = 0;     isK = true; }
  else             { X = xT2; W = Wk2b; bias = bk2; outp = k2t; jt = 0;     isK = true; }
  int j0 = jt * 32;
  int l0 = blockIdx.x * 128 + w * 32;
  const ushort* Xn = X + (size_t)n * L_ * C_;
  f32x4 acc[2][2] = {};
#pragma unroll
  for (int kc = 0; kc < 8; ++kc){
    short8 a[2], b[2];
#pragma unroll
    for (int js = 0; js < 2; ++js)
      a[js] = *(const short8*)(W + (size_t)(j0 + js*16 + low)*C_ + kc*32 + quad*8);
#pragma unroll
    for (int ls = 0; ls < 2; ++ls)
      b[ls] = *(const short8*)(Xn + (size_t)(l0 + ls*16 + low)*C_ + kc*32 + quad*8);
#pragma unroll
    for (int js = 0; js < 2; ++js)
#pragma unroll
      for (int ls = 0; ls < 2; ++ls)
        acc[js][ls] = mfma16(a[js], b[ls], acc[js][ls]);
  }
#pragma unroll
  for (int js = 0; js < 2; ++js){
    f32x4 bb = *(const f32x4*)(bias + j0 + js*16 + quad*4);
#pragma unroll
    for (int ls = 0; ls < 2; ++ls){
      int l = l0 + ls*16 + low;
      if (!isK){
#pragma unroll
        for (int r = 0; r < 4; ++r){
          int j = j0 + js*16 + quad*4 + r;
          outp[((size_t)n*C_ + j)*L_ + l] = f2bf(acc[js][ls][r] + bb[r]);
        }
      } else {
        union { ushort u[4]; uint2v v; } pk;
#pragma unroll
        for (int r = 0; r < 4; ++r) pk.u[r] = f2bf(acc[js][ls][r] + bb[r]);
        *(uint2v*)(outp + ((size_t)n*L_ + l)*CK_ + j0 + js*16 + quad*4) = pk.v;
      }
    }
  }
}

// ---------- stats: partial row/col sums of exp(cor) ----------
__global__ __launch_bounds__(256) void stats_kernel(
    const ushort* __restrict__ k1t, const ushort* __restrict__ k2t,
    float* __restrict__ S1part, float* __restrict__ S2part){
  int n = blockIdx.z;
  int m0 = blockIdx.x * 128, l0 = blockIdx.y * 128;
  int t = threadIdx.x, w = t >> 6, lane = t & 63, quad = lane >> 4, low = lane & 15;
  __shared__ float rowsum[128];
  __shared__ float colsum[4][128];
  const ushort* ka = k1t + (size_t)n * L_ * CK_;
  const ushort* kb = k2t + (size_t)n * L_ * CK_;
  short8 a[2], b[8];
#pragma unroll
  for (int lt = 0; lt < 2; ++lt)
    a[lt] = *(const short8*)(ka + (size_t)(l0 + w*32 + lt*16 + low)*CK_ + quad*8);
#pragma unroll
  for (int mt = 0; mt < 8; ++mt)
    b[mt] = *(const short8*)(kb + (size_t)(m0 + mt*16 + low)*CK_ + quad*8);
  float rp[2][4] = {}; float cp[8] = {};
  const f32x4 zero = {0.f, 0.f, 0.f, 0.f};
#pragma unroll
  for (int lt = 0; lt < 2; ++lt)
#pragma unroll
    for (int mt = 0; mt < 8; ++mt){
      f32x4 e = mfma16(a[lt], b[mt], zero);
#pragma unroll
      for (int r = 0; r < 4; ++r){
        float v = __builtin_amdgcn_exp2f(e[r] * 1.44269504088896f);
        rp[lt][r] += v;
        cp[mt] += v;
      }
    }
#pragma unroll
  for (int lt = 0; lt < 2; ++lt)
#pragma unroll
    for (int r = 0; r < 4; ++r){
      float v = rp[lt][r];
      v += __shfl_xor(v, 1); v += __shfl_xor(v, 2);
      v += __shfl_xor(v, 4); v += __shfl_xor(v, 8);
      if (low == 0) rowsum[w*32 + lt*16 + quad*4 + r] = v;
    }
#pragma unroll
  for (int mt = 0; mt < 8; ++mt){
    float v = cp[mt];
    v += __shfl_xor(v, 16); v += __shfl_xor(v, 32);
    if (quad == 0) colsum[w][mt*16 + low] = v;
  }
  __syncthreads();
  if (t < 128)
    S1part[((size_t)n*32 + blockIdx.x)*L_ + l0 + t] = rowsum[t];
  else {
    int m = t - 128;
    S2part[((size_t)n*32 + blockIdx.y)*L_ + m0 + m] =
        colsum[0][m] + colsum[1][m] + colsum[2][m] + colsum[3][m];
  }
}

// ---------- reduce partials -> lsv = log2(1/S) = -log2(S) ----------
// (r-kernel computes P = exp2(cor*log2e + lsv) = exp(cor)/S)
__global__ __launch_bounds__(256) void reduce_inv_kernel(
    const float* __restrict__ S1part, const float* __restrict__ S2part,
    float* __restrict__ invS1, float* __restrict__ invS2){
  int idx = blockIdx.x * 256 + threadIdx.x;          // 0..16383
  int which = idx >> 13;
  int r = idx & 8191;                                // n*L + l
  int n = r >> 12, l = r & 4095;
  const float* P = which ? S2part : S1part;
  float s = 0.f;
#pragma unroll
  for (int j = 0; j < 32; ++j) s += P[((size_t)n*32 + j)*L_ + l];
  (which ? invS2 : invS1)[(size_t)n*L_ + l] = -__builtin_amdgcn_logf(s);
}

#define LOG2E_ 1.44269504088896f

// ---------- unified flash r-kernel v6: v5 (in-register P, zero main-loop
// barriers) + XCD-aware block swizzle + packed bf16 cvt.
// Diagnosis driving this version: v4 (LDS P) and v5 (register P) ran at
// IDENTICAL 84.3/84.4 us with MfmaUtil 20%, VALUBusy 20/31%, HBM 9.5% —
// every visible pipe has slack. The shared resource both saturate: cold V
// reads. Each block streams a 1 MB V panel once; with default round-robin
// block->XCD placement the 8 (which,n,c-half) V slices (8 MB > 4 MB L2/XCD)
// are read through Infinity Cache at ~600+ cy latency / limited BW.
// Fix: flat 512-block grid, slice = bid & 7 -> one slice per XCD (bid%8
// round-robins XCDs). Per-XCD working set = 1 MB V + 0.5 MB k + 16 KB invS
// -> fully L2-resident, reused by that XCD's 64 q-blocks.
// Also: pack P via __float22bfloat162_rn (compiler emits v_cvt_pk_bf16_f32)
// instead of manual bit-RNE (~100 fewer VALU instr per chunk).
__global__ __launch_bounds__(256, 2) void cross_attn_r_kernel(
    const ushort* __restrict__ k1t, const ushort* __restrict__ k2t,
    const ushort* __restrict__ v1,  const ushort* __restrict__ v2,
    const float* __restrict__ invS1, const float* __restrict__ invS2,
    const float* __restrict__ x1, const float* __restrict__ x2,
    float* __restrict__ out){
  int bid = blockIdx.x;
  int slice = bid & 7;                 // -> XCD (bid % 8 round-robin)
  int qb = bid >> 3;                   // 0..63
  int n = slice & 1;
  int which = (slice >> 1) & 1;
  int chalf = slice >> 2;
  const ushort* kA = which ? k2t : k1t;
  const ushort* kB = which ? k1t : k2t;
  const ushort* V  = which ? v2  : v1;
  const float* iS  = which ? invS2 : invS1;
  const float* X   = which ? x2 : x1;
  float* O = out + (size_t)which * N_ * C_ * L_;
  int q0 = qb * 64, c0 = chalf * 128;
  int t = threadIdx.x, w = t >> 6, lane = t & 63, quad = lane >> 4, low = lane & 15;
  __shared__ __align__(16) float red[4][16][68];   // [wave][c_local][q(+pad)]
  const ushort* kAn = kA + (size_t)n * L_ * CK_;
  const ushort* kBn = kB + (size_t)n * L_ * CK_;
  const ushort* Vn  = V  + (size_t)n * C_ * L_;
  const float*  iSn = iS + (size_t)n * L_;

  // permuted-row A base: A-row m=low -> kA row (m>>2)*8 + (m&3)
  const ushort* kA_base = kAn + (size_t)((low >> 2) * 8 + (low & 3)) * CK_ + quad * 8;
  const float*  sv_base = iSn + quad * 8;
  const ushort* V_base  = Vn + (size_t)(c0 + low) * L_ + quad * 8;

  // E-phase B operand (q rows of kB) is loop-invariant: preload once.
  short8 be[4];
#pragma unroll
  for (int qs = 0; qs < 4; ++qs)
    be[qs] = *(const short8*)(kBn + (size_t)(q0 + qs*16 + low) * CK_ + quad * 8);

  f32x4 acc[8][4] = {};
  const f32x4 zero = {0.f, 0.f, 0.f, 0.f};

  // software-pipelined kA-row + scale loads (16 VGPR)
  int pfirst = w * 32;
  short8 a0 = *(const short8*)(kA_base + (size_t)pfirst * CK_);
  short8 a1 = *(const short8*)(kA_base + (size_t)(pfirst + 4) * CK_);
  f32x4 sv0 = *(const f32x4*)(sv_base + pfirst);
  f32x4 sv1 = *(const f32x4*)(sv_base + pfirst + 4);

  for (int kk = 0; kk < L_ / 128; ++kk){
    int p = kk * 128 + w * 32;
    // V for this iteration: issued first, consumed after e-phase
    short8 vv[8];
#pragma unroll
    for (int ct = 0; ct < 8; ++ct)
      vv[ct] = *(const short8*)(V_base + (size_t)ct * 16 * L_ + p);
    // e-phase: P rows p..p+31 (this wave's slice), cols q0..q0+63, in-register
    short8 pb[4];
#pragma unroll
    for (int qs = 0; qs < 4; ++qs){
      f32x4 e0 = mfma16(a0, be[qs], zero);   // rows p+quad*8+r
      f32x4 e1 = mfma16(a1, be[qs], zero);   // rows p+quad*8+4+r
      float p0 = __builtin_amdgcn_exp2f(__fmaf_rn(e0[0], LOG2E_, sv0[0]));
      float p1 = __builtin_amdgcn_exp2f(__fmaf_rn(e0[1], LOG2E_, sv0[1]));
      float p2 = __builtin_amdgcn_exp2f(__fmaf_rn(e0[2], LOG2E_, sv0[2]));
      float p3 = __builtin_amdgcn_exp2f(__fmaf_rn(e0[3], LOG2E_, sv0[3]));
      float p4 = __builtin_amdgcn_exp2f(__fmaf_rn(e1[0], LOG2E_, sv1[0]));
      float p5 = __builtin_amdgcn_exp2f(__fmaf_rn(e1[1], LOG2E_, sv1[1]));
      float p6 = __builtin_amdgcn_exp2f(__fmaf_rn(e1[2], LOG2E_, sv1[2]));
      float p7 = __builtin_amdgcn_exp2f(__fmaf_rn(e1[3], LOG2E_, sv1[3]));
      union { __hip_bfloat162 h[4]; short8 v; } pk;
      pk.h[0] = __float22bfloat162_rn(make_float2(p0, p1));
      pk.h[1] = __float22bfloat162_rn(make_float2(p2, p3));
      pk.h[2] = __float22bfloat162_rn(make_float2(p4, p5));
      pk.h[3] = __float22bfloat162_rn(make_float2(p6, p7));
      pb[qs] = pk.v;
    }
    // prefetch next iteration's kA rows + scales (hidden under PV MFMAs)
    int pn = ((kk + 1) & 31) * 128 + w * 32;   // wraps on last iter (harmless)
    a0 = *(const short8*)(kA_base + (size_t)pn * CK_);
    a1 = *(const short8*)(kA_base + (size_t)(pn + 4) * CK_);
    sv0 = *(const f32x4*)(sv_base + pn);
    sv1 = *(const f32x4*)(sv_base + pn + 4);
    // PV: acc[c-tile][q-tile] += V[c, p-slice] * P[p-slice, q]
#pragma unroll
    for (int ct = 0; ct < 8; ++ct)
#pragma unroll
      for (int qs = 0; qs < 4; ++qs)
        acc[ct][qs] = mfma16(vv[ct], pb[qs], acc[ct][qs]);
  }

  // --- epilogue: cross-wave reduction of the 4 disjoint-p partials + x add
  int cl = t >> 4, qg = (t & 15) * 4;
#pragma unroll
  for (int ct = 0; ct < 8; ++ct){
#pragma unroll
    for (int qs = 0; qs < 4; ++qs)
#pragma unroll
      for (int r = 0; r < 4; ++r)
        red[w][quad*4 + r][qs*16 + low] = acc[ct][qs][r];
    __syncthreads();
    f32x4 s0 = *(const f32x4*)&red[0][cl][qg];
    f32x4 s1 = *(const f32x4*)&red[1][cl][qg];
    f32x4 s2 = *(const f32x4*)&red[2][cl][qg];
    f32x4 s3 = *(const f32x4*)&red[3][cl][qg];
    f32x4 s = (s0 + s1) + (s2 + s3);
    size_t idx = ((size_t)n * C_ + c0 + ct*16 + cl) * L_ + q0 + qg;
    const float4 xv = *(const float4*)(X + idx);
    float4 o = make_float4(xv.x + s[0], xv.y + s[1], xv.z + s[2], xv.w + s[3]);
    *(float4*)(O + idx) = o;
    __syncthreads();
  }
}

extern "C" void kernel_launch(void* const* d_in, const int* in_sizes, int n_in,
                              void* d_out, int out_size, void* d_ws, size_t ws_size,
                              hipStream_t stream) {
  const float* x1  = (const float*)d_in[0];
  const float* x2  = (const float*)d_in[1];
  const float* Wk1 = (const float*)d_in[2];
  const float* bk1 = (const float*)d_in[3];
  const float* Wk2 = (const float*)d_in[4];
  const float* bk2 = (const float*)d_in[5];
  const float* Wv1 = (const float*)d_in[6];
  const float* bv1 = (const float*)d_in[7];
  const float* Wv2 = (const float*)d_in[8];
  const float* bv2 = (const float*)d_in[9];

  char* ws = (char*)d_ws;
  size_t off = 0;
  auto carve = [&](size_t bytes) -> void* {
    void* p = ws + off; off += (bytes + 255) & ~(size_t)255; return p;
  };
  ushort* xT1   = (ushort*)carve((size_t)N_*L_*C_*2);
  ushort* xT2   = (ushort*)carve((size_t)N_*L_*C_*2);
  ushort* Wk1b  = (ushort*)carve((size_t)CK_*C_*2);
  ushort* Wk2b  = (ushort*)carve((size_t)CK_*C_*2);
  ushort* Wv1b  = (ushort*)carve((size_t)C_*C_*2);
  ushort* Wv2b  = (ushort*)carve((size_t)C_*C_*2);
  ushort* k1t   = (ushort*)carve((size_t)N_*L_*CK_*2);
  ushort* k2t   = (ushort*)carve((size_t)N_*L_*CK_*2);
  ushort* v1    = (ushort*)carve((size_t)N_*C_*L_*2);
  ushort* v2    = (ushort*)carve((size_t)N_*C_*L_*2);
  float*  S1p   = (float*)carve((size_t)N_*32*L_*4);
  float*  S2p   = (float*)carve((size_t)N_*32*L_*4);
  float*  invS1 = (float*)carve((size_t)N_*L_*4);
  float*  invS2 = (float*)carve((size_t)N_*L_*4);

  convert_x_kernel<<<dim3(L_/64, C_/128, 4), 256, 0, stream>>>(x1, x2, xT1, xT2);
  convert_w_kernel<<<dim3((2*CK_*C_ + 2*C_*C_) / 256), 256, 0, stream>>>(
      Wk1, Wk2, Wv1, Wv2, Wk1b, Wk2b, Wv1b, Wv2b);
  proj_kernel<<<dim3(L_/128, 18, N_), 256, 0, stream>>>(
      xT1, xT2, Wk1b, Wk2b, Wv1b, Wv2b, bk1, bk2, bv1, bv2, k1t, k2t, v1, v2);
  stats_kernel<<<dim3(L_/128, L_/128, N_), 256, 0, stream>>>(k1t, k2t, S1p, S2p);
  reduce_inv_kernel<<<dim3(2*N_*L_/256), 256, 0, stream>>>(S1p, S2p, invS1, invS2);
  cross_attn_r_kernel<<<dim3(2 * N_ * (C_/128) * (L_/64), 1, 1), 256, 0, stream>>>(
      k1t, k2t, v1, v2, invS1, invS2, x1, x2, (float*)d_out);
}

// Round 4
// 177.231 us; speedup vs baseline: 1.1275x; 1.1256x over previous
//
#include <hip/hip_runtime.h>
#include <hip/hip_bf16.h>

#define N_  2
#define C_  256
#define CK_ 32
#define L_  4096

typedef __attribute__((ext_vector_type(8))) short short8;   // 8 bf16 (4 VGPRs)
typedef __attribute__((ext_vector_type(4))) float f32x4;    // MFMA C/D
typedef __attribute__((ext_vector_type(2))) unsigned int uint2v;
typedef unsigned short ushort;

__device__ __forceinline__ ushort f2bf(float f){
  unsigned u = __float_as_uint(f);
  u += 0x7fffu + ((u >> 16) & 1u);     // RNE
  return (ushort)(u >> 16);
}

__device__ __forceinline__ f32x4 mfma16(short8 a, short8 b, f32x4 c){
  return __builtin_amdgcn_mfma_f32_16x16x32_bf16(a, b, c, 0, 0, 0);
}

// ---------- convert+transpose x: [n][C][L] f32 -> [n][L][C] bf16 ----------
__global__ __launch_bounds__(256) void convert_x_kernel(
    const float* __restrict__ x1, const float* __restrict__ x2,
    ushort* __restrict__ xT1, ushort* __restrict__ xT2){
  __shared__ float tt[64][130];        // [l][c]
  int z = blockIdx.z; int n = z & 1;
  const float* x = (z >> 1) ? x2 : x1;
  ushort* xT = (z >> 1) ? xT2 : xT1;
  int l0 = blockIdx.x * 64, c0 = blockIdx.y * 128;
  int t = threadIdx.x;
  const float* xs = x + (size_t)n * C_ * L_;
  ushort* xd = xT + (size_t)n * L_ * C_;
  int lq = (t & 15) * 4, cl = t >> 4;              // cl 0..15
#pragma unroll
  for (int r = 0; r < 8; ++r){
    int c = r * 16 + cl;
    float4 f = *(const float4*)(xs + (size_t)(c0 + c) * L_ + l0 + lq);
    tt[lq + 0][c] = f.x; tt[lq + 1][c] = f.y; tt[lq + 2][c] = f.z; tt[lq + 3][c] = f.w;
  }
  __syncthreads();
  int c8 = (t & 15) * 8, ll = t >> 4;              // ll 0..15
#pragma unroll
  for (int r = 0; r < 4; ++r){
    int l = r * 16 + ll;
    union { ushort u[8]; short8 v; } pk;
#pragma unroll
    for (int j = 0; j < 8; ++j) pk.u[j] = f2bf(tt[l][c8 + j]);
    *(short8*)(xd + (size_t)(l0 + l) * C_ + c0 + c8) = pk.v;
  }
}

// ---------- convert weights f32 -> bf16 (flat) ----------
__global__ __launch_bounds__(256) void convert_w_kernel(
    const float* __restrict__ Wk1, const float* __restrict__ Wk2,
    const float* __restrict__ Wv1, const float* __restrict__ Wv2,
    ushort* __restrict__ o1, ushort* __restrict__ o2,
    ushort* __restrict__ o3, ushort* __restrict__ o4){
  int idx = blockIdx.x * 256 + threadIdx.x;
  const int KS = CK_ * C_;      // 8192
  const int VS = C_ * C_;       // 65536
  if (idx < KS)                 o1[idx] = f2bf(Wk1[idx]);
  else if (idx < 2*KS)          o2[idx - KS] = f2bf(Wk2[idx - KS]);
  else if (idx < 2*KS + VS)     o3[idx - 2*KS] = f2bf(Wv1[idx - 2*KS]);
  else if (idx < 2*KS + 2*VS)   o4[idx - 2*KS - VS] = f2bf(Wv2[idx - 2*KS - VS]);
}

// V packed layout: per n, 128 pblk (32 p-cols) x 16 cblk (16 c-rows) tiles of
// 512 elts (1 KB). In-tile: elt (c,p) at quad*128 + (c&15)*8 + (p&7), where
// quad = (p&31)>>3. A wave-load of short8 at tile_base + lane*8 (lane =
// quad*16+row) is fully contiguous 1 KB and delivers exactly the PV MFMA
// A-fragment: lane(quad,low) <- V[cblk*16+low][pblk*32 + quad*8 + j].
#define VP_OFF(nn, cc, pp) \
  ((((size_t)(nn)*128 + ((pp)>>5))*16 + ((cc)>>4))*512 + \
   (((pp)&31)>>3)*128 + ((cc)&15)*8 + ((pp)&7))

// ---------- fused projections: k1t/k2t [n][L][CK], v1/v2 packed tiles ----------
__global__ __launch_bounds__(256) void proj_kernel(
    const ushort* __restrict__ xT1, const ushort* __restrict__ xT2,
    const ushort* __restrict__ Wk1b, const ushort* __restrict__ Wk2b,
    const ushort* __restrict__ Wv1b, const ushort* __restrict__ Wv2b,
    const float* __restrict__ bk1, const float* __restrict__ bk2,
    const float* __restrict__ bv1, const float* __restrict__ bv2,
    ushort* __restrict__ k1t, ushort* __restrict__ k2t,
    ushort* __restrict__ v1,  ushort* __restrict__ v2){
  int y = blockIdx.y, n = blockIdx.z;
  int t = threadIdx.x, w = t >> 6, lane = t & 63, quad = lane >> 4, low = lane & 15;
  const ushort* X; const ushort* W; const float* bias; ushort* outp; int jt; bool isK;
  if (y < 8)       { X = xT1; W = Wv1b; bias = bv1; outp = v1;  jt = y;     isK = false; }
  else if (y < 16) { X = xT2; W = Wv2b; bias = bv2; outp = v2;  jt = y - 8; isK = false; }
  else if (y == 16){ X = xT1; W = Wk1b; bias = bk1; outp = k1t; jt = 0;     isK = true; }
  else             { X = xT2; W = Wk2b; bias = bk2; outp = k2t; jt = 0;     isK = true; }
  int j0 = jt * 32;
  int l0 = blockIdx.x * 128 + w * 32;
  const ushort* Xn = X + (size_t)n * L_ * C_;
  f32x4 acc[2][2] = {};
#pragma unroll
  for (int kc = 0; kc < 8; ++kc){
    short8 a[2], b[2];
#pragma unroll
    for (int js = 0; js < 2; ++js)
      a[js] = *(const short8*)(W + (size_t)(j0 + js*16 + low)*C_ + kc*32 + quad*8);
#pragma unroll
    for (int ls = 0; ls < 2; ++ls)
      b[ls] = *(const short8*)(Xn + (size_t)(l0 + ls*16 + low)*C_ + kc*32 + quad*8);
#pragma unroll
    for (int js = 0; js < 2; ++js)
#pragma unroll
      for (int ls = 0; ls < 2; ++ls)
        acc[js][ls] = mfma16(a[js], b[ls], acc[js][ls]);
  }
#pragma unroll
  for (int js = 0; js < 2; ++js){
    f32x4 bb = *(const f32x4*)(bias + j0 + js*16 + quad*4);
#pragma unroll
    for (int ls = 0; ls < 2; ++ls){
      int l = l0 + ls*16 + low;
      if (!isK){
#pragma unroll
        for (int r = 0; r < 4; ++r){
          int c = j0 + js*16 + quad*4 + r;        // output channel
          outp[VP_OFF(n, c, l)] = f2bf(acc[js][ls][r] + bb[r]);
        }
      } else {
        union { ushort u[4]; uint2v v; } pk;
#pragma unroll
        for (int r = 0; r < 4; ++r) pk.u[r] = f2bf(acc[js][ls][r] + bb[r]);
        *(uint2v*)(outp + ((size_t)n*L_ + l)*CK_ + j0 + js*16 + quad*4) = pk.v;
      }
    }
  }
}

// ---------- stats: partial row/col sums of exp(cor) ----------
__global__ __launch_bounds__(256) void stats_kernel(
    const ushort* __restrict__ k1t, const ushort* __restrict__ k2t,
    float* __restrict__ S1part, float* __restrict__ S2part){
  int n = blockIdx.z;
  int m0 = blockIdx.x * 128, l0 = blockIdx.y * 128;
  int t = threadIdx.x, w = t >> 6, lane = t & 63, quad = lane >> 4, low = lane & 15;
  __shared__ float rowsum[128];
  __shared__ float colsum[4][128];
  const ushort* ka = k1t + (size_t)n * L_ * CK_;
  const ushort* kb = k2t + (size_t)n * L_ * CK_;
  short8 a[2], b[8];
#pragma unroll
  for (int lt = 0; lt < 2; ++lt)
    a[lt] = *(const short8*)(ka + (size_t)(l0 + w*32 + lt*16 + low)*CK_ + quad*8);
#pragma unroll
  for (int mt = 0; mt < 8; ++mt)
    b[mt] = *(const short8*)(kb + (size_t)(m0 + mt*16 + low)*CK_ + quad*8);
  float rp[2][4] = {}; float cp[8] = {};
  const f32x4 zero = {0.f, 0.f, 0.f, 0.f};
#pragma unroll
  for (int lt = 0; lt < 2; ++lt)
#pragma unroll
    for (int mt = 0; mt < 8; ++mt){
      f32x4 e = mfma16(a[lt], b[mt], zero);
#pragma unroll
      for (int r = 0; r < 4; ++r){
        float v = __builtin_amdgcn_exp2f(e[r] * 1.44269504088896f);
        rp[lt][r] += v;
        cp[mt] += v;
      }
    }
#pragma unroll
  for (int lt = 0; lt < 2; ++lt)
#pragma unroll
    for (int r = 0; r < 4; ++r){
      float v = rp[lt][r];
      v += __shfl_xor(v, 1); v += __shfl_xor(v, 2);
      v += __shfl_xor(v, 4); v += __shfl_xor(v, 8);
      if (low == 0) rowsum[w*32 + lt*16 + quad*4 + r] = v;
    }
#pragma unroll
  for (int mt = 0; mt < 8; ++mt){
    float v = cp[mt];
    v += __shfl_xor(v, 16); v += __shfl_xor(v, 32);
    if (quad == 0) colsum[w][mt*16 + low] = v;
  }
  __syncthreads();
  if (t < 128)
    S1part[((size_t)n*32 + blockIdx.x)*L_ + l0 + t] = rowsum[t];
  else {
    int m = t - 128;
    S2part[((size_t)n*32 + blockIdx.y)*L_ + m0 + m] =
        colsum[0][m] + colsum[1][m] + colsum[2][m] + colsum[3][m];
  }
}

// ---------- reduce partials -> lsv = log2(1/S) = -log2(S) ----------
__global__ __launch_bounds__(256) void reduce_inv_kernel(
    const float* __restrict__ S1part, const float* __restrict__ S2part,
    float* __restrict__ invS1, float* __restrict__ invS2){
  int idx = blockIdx.x * 256 + threadIdx.x;          // 0..16383
  int which = idx >> 13;
  int r = idx & 8191;                                // n*L + l
  int n = r >> 12, l = r & 4095;
  const float* P = which ? S2part : S1part;
  float s = 0.f;
#pragma unroll
  for (int j = 0; j < 32; ++j) s += P[((size_t)n*32 + j)*L_ + l];
  (which ? invS2 : invS1)[(size_t)n*L_ + l] = -__builtin_amdgcn_logf(s);
}

#define LOG2E_ 1.44269504088896f

// ---------- unified flash r-kernel v7: v6 + PACKED V tiles.
// Diagnosis: v4/v5/v6 (LDS-P, reg-P, reg-P+XCD-swizzle) all ran at exactly
// 84 us with MfmaUtil 20%, VALUBusy 23%, HBM <10%. v6 proved locality is
// not the issue (FETCH 45.6->14.4 MB, time unchanged). Cycle budget says
// 6300 cy/iter vs ~650 cy of issue work: ~4600 cy/iter memory stall that
// is invariant to data residency. The shared invariant: V[n][C][L] loads
// touch 16 rows x 64 B at 8 KB stride per instruction (and 128 KB stride
// across ct) -> L2 channel aliasing / TA segment serialization, identical
// cost whether lines are in L2 or HBM.
// Fix: V is produced in MFMA-fragment-ordered 1 KB tiles (VP_OFF); each of
// the 8 PV loads per iteration is a fully contiguous 1 KB wave-load, all 8
// from consecutive addresses (single base + immediate offsets).
__global__ __launch_bounds__(256, 2) void cross_attn_r_kernel(
    const ushort* __restrict__ k1t, const ushort* __restrict__ k2t,
    const ushort* __restrict__ v1,  const ushort* __restrict__ v2,
    const float* __restrict__ invS1, const float* __restrict__ invS2,
    const float* __restrict__ x1, const float* __restrict__ x2,
    float* __restrict__ out){
  int bid = blockIdx.x;
  int slice = bid & 7;                 // -> XCD (bid % 8 round-robin)
  int qb = bid >> 3;                   // 0..63
  int n = slice & 1;
  int which = (slice >> 1) & 1;
  int chalf = slice >> 2;
  const ushort* kA = which ? k2t : k1t;
  const ushort* kB = which ? k1t : k2t;
  const ushort* V  = which ? v2  : v1;
  const float* iS  = which ? invS2 : invS1;
  const float* X   = which ? x2 : x1;
  float* O = out + (size_t)which * N_ * C_ * L_;
  int q0 = qb * 64, c0 = chalf * 128;
  int t = threadIdx.x, w = t >> 6, lane = t & 63, quad = lane >> 4, low = lane & 15;
  __shared__ __align__(16) float red[4][16][68];   // [wave][c_local][q(+pad)]
  const ushort* kAn = kA + (size_t)n * L_ * CK_;
  const ushort* kBn = kB + (size_t)n * L_ * CK_;
  const float*  iSn = iS + (size_t)n * L_;

  // permuted-row A base: A-row m=low -> kA row (m>>2)*8 + (m&3)
  const ushort* kA_base = kAn + (size_t)((low >> 2) * 8 + (low & 3)) * CK_ + quad * 8;
  const float*  sv_base = iSn + quad * 8;
  // packed-V lane base: tiles for this (n, chalf) start at cblk = chalf*8
  const ushort* Vp_lane = V + ((size_t)n * 128 * 16 + chalf * 8) * 512 + (size_t)lane * 8;

  // E-phase B operand (q rows of kB) is loop-invariant: preload once.
  short8 be[4];
#pragma unroll
  for (int qs = 0; qs < 4; ++qs)
    be[qs] = *(const short8*)(kBn + (size_t)(q0 + qs*16 + low) * CK_ + quad * 8);

  f32x4 acc[8][4] = {};
  const f32x4 zero = {0.f, 0.f, 0.f, 0.f};

  // software-pipelined kA-row + scale loads (16 VGPR)
  int pfirst = w * 32;
  short8 a0 = *(const short8*)(kA_base + (size_t)pfirst * CK_);
  short8 a1 = *(const short8*)(kA_base + (size_t)(pfirst + 4) * CK_);
  f32x4 sv0 = *(const f32x4*)(sv_base + pfirst);
  f32x4 sv1 = *(const f32x4*)(sv_base + pfirst + 4);

  for (int kk = 0; kk < L_ / 128; ++kk){
    // V for this iteration: 8 consecutive 1 KB tiles (pblk = kk*4 + w)
    const ushort* vt = Vp_lane + (size_t)(kk*4 + w) * 16 * 512;
    short8 vv[8];
#pragma unroll
    for (int ct = 0; ct < 8; ++ct)
      vv[ct] = *(const short8*)(vt + ct * 512);
    // e-phase: P rows p..p+31 (this wave's slice), cols q0..q0+63, in-register
    short8 pb[4];
#pragma unroll
    for (int qs = 0; qs < 4; ++qs){
      f32x4 e0 = mfma16(a0, be[qs], zero);   // rows p+quad*8+r
      f32x4 e1 = mfma16(a1, be[qs], zero);   // rows p+quad*8+4+r
      float p0 = __builtin_amdgcn_exp2f(__fmaf_rn(e0[0], LOG2E_, sv0[0]));
      float p1 = __builtin_amdgcn_exp2f(__fmaf_rn(e0[1], LOG2E_, sv0[1]));
      float p2 = __builtin_amdgcn_exp2f(__fmaf_rn(e0[2], LOG2E_, sv0[2]));
      float p3 = __builtin_amdgcn_exp2f(__fmaf_rn(e0[3], LOG2E_, sv0[3]));
      float p4 = __builtin_amdgcn_exp2f(__fmaf_rn(e1[0], LOG2E_, sv1[0]));
      float p5 = __builtin_amdgcn_exp2f(__fmaf_rn(e1[1], LOG2E_, sv1[1]));
      float p6 = __builtin_amdgcn_exp2f(__fmaf_rn(e1[2], LOG2E_, sv1[2]));
      float p7 = __builtin_amdgcn_exp2f(__fmaf_rn(e1[3], LOG2E_, sv1[3]));
      union { __hip_bfloat162 h[4]; short8 v; } pk;
      pk.h[0] = __float22bfloat162_rn(make_float2(p0, p1));
      pk.h[1] = __float22bfloat162_rn(make_float2(p2, p3));
      pk.h[2] = __float22bfloat162_rn(make_float2(p4, p5));
      pk.h[3] = __float22bfloat162_rn(make_float2(p6, p7));
      pb[qs] = pk.v;
    }
    // prefetch next iteration's kA rows + scales (hidden under PV MFMAs)
    int pn = ((kk + 1) & 31) * 128 + w * 32;   // wraps on last iter (harmless)
    a0 = *(const short8*)(kA_base + (size_t)pn * CK_);
    a1 = *(const short8*)(kA_base + (size_t)(pn + 4) * CK_);
    sv0 = *(const f32x4*)(sv_base + pn);
    sv1 = *(const f32x4*)(sv_base + pn + 4);
    // PV: acc[c-tile][q-tile] += V[c, p-slice] * P[p-slice, q]
#pragma unroll
    for (int ct = 0; ct < 8; ++ct)
#pragma unroll
      for (int qs = 0; qs < 4; ++qs)
        acc[ct][qs] = mfma16(vv[ct], pb[qs], acc[ct][qs]);
  }

  // --- epilogue: cross-wave reduction of the 4 disjoint-p partials + x add
  int cl = t >> 4, qg = (t & 15) * 4;
#pragma unroll
  for (int ct = 0; ct < 8; ++ct){
#pragma unroll
    for (int qs = 0; qs < 4; ++qs)
#pragma unroll
      for (int r = 0; r < 4; ++r)
        red[w][quad*4 + r][qs*16 + low] = acc[ct][qs][r];
    __syncthreads();
    f32x4 s0 = *(const f32x4*)&red[0][cl][qg];
    f32x4 s1 = *(const f32x4*)&red[1][cl][qg];
    f32x4 s2 = *(const f32x4*)&red[2][cl][qg];
    f32x4 s3 = *(const f32x4*)&red[3][cl][qg];
    f32x4 s = (s0 + s1) + (s2 + s3);
    size_t idx = ((size_t)n * C_ + c0 + ct*16 + cl) * L_ + q0 + qg;
    const float4 xv = *(const float4*)(X + idx);
    float4 o = make_float4(xv.x + s[0], xv.y + s[1], xv.z + s[2], xv.w + s[3]);
    *(float4*)(O + idx) = o;
    __syncthreads();
  }
}

extern "C" void kernel_launch(void* const* d_in, const int* in_sizes, int n_in,
                              void* d_out, int out_size, void* d_ws, size_t ws_size,
                              hipStream_t stream) {
  const float* x1  = (const float*)d_in[0];
  const float* x2  = (const float*)d_in[1];
  const float* Wk1 = (const float*)d_in[2];
  const float* bk1 = (const float*)d_in[3];
  const float* Wk2 = (const float*)d_in[4];
  const float* bk2 = (const float*)d_in[5];
  const float* Wv1 = (const float*)d_in[6];
  const float* bv1 = (const float*)d_in[7];
  const float* Wv2 = (const float*)d_in[8];
  const float* bv2 = (const float*)d_in[9];

  char* ws = (char*)d_ws;
  size_t off = 0;
  auto carve = [&](size_t bytes) -> void* {
    void* p = ws + off; off += (bytes + 255) & ~(size_t)255; return p;
  };
  ushort* xT1   = (ushort*)carve((size_t)N_*L_*C_*2);
  ushort* xT2   = (ushort*)carve((size_t)N_*L_*C_*2);
  ushort* Wk1b  = (ushort*)carve((size_t)CK_*C_*2);
  ushort* Wk2b  = (ushort*)carve((size_t)CK_*C_*2);
  ushort* Wv1b  = (ushort*)carve((size_t)C_*C_*2);
  ushort* Wv2b  = (ushort*)carve((size_t)C_*C_*2);
  ushort* k1t   = (ushort*)carve((size_t)N_*L_*CK_*2);
  ushort* k2t   = (ushort*)carve((size_t)N_*L_*CK_*2);
  ushort* v1    = (ushort*)carve((size_t)N_*C_*L_*2);
  ushort* v2    = (ushort*)carve((size_t)N_*C_*L_*2);
  float*  S1p   = (float*)carve((size_t)N_*32*L_*4);
  float*  S2p   = (float*)carve((size_t)N_*32*L_*4);
  float*  invS1 = (float*)carve((size_t)N_*L_*4);
  float*  invS2 = (float*)carve((size_t)N_*L_*4);

  convert_x_kernel<<<dim3(L_/64, C_/128, 4), 256, 0, stream>>>(x1, x2, xT1, xT2);
  convert_w_kernel<<<dim3((2*CK_*C_ + 2*C_*C_) / 256), 256, 0, stream>>>(
      Wk1, Wk2, Wv1, Wv2, Wk1b, Wk2b, Wv1b, Wv2b);
  proj_kernel<<<dim3(L_/128, 18, N_), 256, 0, stream>>>(
      xT1, xT2, Wk1b, Wk2b, Wv1b, Wv2b, bk1, bk2, bv1, bv2, k1t, k2t, v1, v2);
  stats_kernel<<<dim3(L_/128, L_/128, N_), 256, 0, stream>>>(k1t, k2t, S1p, S2p);
  reduce_inv_kernel<<<dim3(2*N_*L_/256), 256, 0, stream>>>(S1p, S2p, invS1, invS2);
  cross_attn_r_kernel<<<dim3(2 * N_ * (C_/128) * (L_/64), 1, 1), 256, 0, stream>>>(
      k1t, k2t, v1, v2, invS1, invS2, x1, x2, (float*)d_out);
}

// Round 5
// 172.044 us; speedup vs baseline: 1.1615x; 1.0302x over previous
//
#include <hip/hip_runtime.h>
#include <hip/hip_bf16.h>

#define N_  2
#define C_  256
#define CK_ 32
#define L_  4096

typedef __attribute__((ext_vector_type(8))) short short8;   // 8 bf16 (4 VGPRs)
typedef __attribute__((ext_vector_type(4))) float f32x4;    // MFMA C/D
typedef __attribute__((ext_vector_type(2))) unsigned int uint2v;
typedef unsigned short ushort;

__device__ __forceinline__ ushort f2bf(float f){
  unsigned u = __float_as_uint(f);
  u += 0x7fffu + ((u >> 16) & 1u);     // RNE
  return (ushort)(u >> 16);
}

__device__ __forceinline__ f32x4 mfma16(short8 a, short8 b, f32x4 c){
  return __builtin_amdgcn_mfma_f32_16x16x32_bf16(a, b, c, 0, 0, 0);
}

// ---------- convert+transpose x: [n][C][L] f32 -> [n][L][C] bf16 ----------
__global__ __launch_bounds__(256) void convert_x_kernel(
    const float* __restrict__ x1, const float* __restrict__ x2,
    ushort* __restrict__ xT1, ushort* __restrict__ xT2){
  __shared__ float tt[64][130];        // [l][c]
  int z = blockIdx.z; int n = z & 1;
  const float* x = (z >> 1) ? x2 : x1;
  ushort* xT = (z >> 1) ? xT2 : xT1;
  int l0 = blockIdx.x * 64, c0 = blockIdx.y * 128;
  int t = threadIdx.x;
  const float* xs = x + (size_t)n * C_ * L_;
  ushort* xd = xT + (size_t)n * L_ * C_;
  int lq = (t & 15) * 4, cl = t >> 4;              // cl 0..15
#pragma unroll
  for (int r = 0; r < 8; ++r){
    int c = r * 16 + cl;
    float4 f = *(const float4*)(xs + (size_t)(c0 + c) * L_ + l0 + lq);
    tt[lq + 0][c] = f.x; tt[lq + 1][c] = f.y; tt[lq + 2][c] = f.z; tt[lq + 3][c] = f.w;
  }
  __syncthreads();
  int c8 = (t & 15) * 8, ll = t >> 4;              // ll 0..15
#pragma unroll
  for (int r = 0; r < 4; ++r){
    int l = r * 16 + ll;
    union { ushort u[8]; short8 v; } pk;
#pragma unroll
    for (int j = 0; j < 8; ++j) pk.u[j] = f2bf(tt[l][c8 + j]);
    *(short8*)(xd + (size_t)(l0 + l) * C_ + c0 + c8) = pk.v;
  }
}

// ---------- convert weights f32 -> bf16 (flat) ----------
__global__ __launch_bounds__(256) void convert_w_kernel(
    const float* __restrict__ Wk1, const float* __restrict__ Wk2,
    const float* __restrict__ Wv1, const float* __restrict__ Wv2,
    ushort* __restrict__ o1, ushort* __restrict__ o2,
    ushort* __restrict__ o3, ushort* __restrict__ o4){
  int idx = blockIdx.x * 256 + threadIdx.x;
  const int KS = CK_ * C_;      // 8192
  const int VS = C_ * C_;       // 65536
  if (idx < KS)                 o1[idx] = f2bf(Wk1[idx]);
  else if (idx < 2*KS)          o2[idx - KS] = f2bf(Wk2[idx - KS]);
  else if (idx < 2*KS + VS)     o3[idx - 2*KS] = f2bf(Wv1[idx - 2*KS]);
  else if (idx < 2*KS + 2*VS)   o4[idx - 2*KS - VS] = f2bf(Wv2[idx - 2*KS - VS]);
}

// V packed layout: per n, 128 pblk (32 p-cols) x 16 cblk (16 c-rows) tiles of
// 512 elts (1 KB). In-tile: elt (c,p) at quad*128 + (c&15)*8 + (p&7), where
// quad = (p&31)>>3. A wave-load of short8 at tile_base + lane*8 (lane =
// quad*16+row) is fully contiguous 1 KB and delivers exactly the PV MFMA
// A-fragment: lane(quad,low) <- V[cblk*16+low][pblk*32 + quad*8 + j].
#define VP_OFF(nn, cc, pp) \
  ((((size_t)(nn)*128 + ((pp)>>5))*16 + ((cc)>>4))*512 + \
   (((pp)&31)>>3)*128 + ((cc)&15)*8 + ((pp)&7))

// ---------- fused projections: k1t/k2t [n][L][CK], v1/v2 packed tiles ----------
__global__ __launch_bounds__(256) void proj_kernel(
    const ushort* __restrict__ xT1, const ushort* __restrict__ xT2,
    const ushort* __restrict__ Wk1b, const ushort* __restrict__ Wk2b,
    const ushort* __restrict__ Wv1b, const ushort* __restrict__ Wv2b,
    const float* __restrict__ bk1, const float* __restrict__ bk2,
    const float* __restrict__ bv1, const float* __restrict__ bv2,
    ushort* __restrict__ k1t, ushort* __restrict__ k2t,
    ushort* __restrict__ v1,  ushort* __restrict__ v2){
  int y = blockIdx.y, n = blockIdx.z;
  int t = threadIdx.x, w = t >> 6, lane = t & 63, quad = lane >> 4, low = lane & 15;
  const ushort* X; const ushort* W; const float* bias; ushort* outp; int jt; bool isK;
  if (y < 8)       { X = xT1; W = Wv1b; bias = bv1; outp = v1;  jt = y;     isK = false; }
  else if (y < 16) { X = xT2; W = Wv2b; bias = bv2; outp = v2;  jt = y - 8; isK = false; }
  else if (y == 16){ X = xT1; W = Wk1b; bias = bk1; outp = k1t; jt = 0;     isK = true; }
  else             { X = xT2; W = Wk2b; bias = bk2; outp = k2t; jt = 0;     isK = true; }
  int j0 = jt * 32;
  int l0 = blockIdx.x * 128 + w * 32;
  const ushort* Xn = X + (size_t)n * L_ * C_;
  f32x4 acc[2][2] = {};
#pragma unroll
  for (int kc = 0; kc < 8; ++kc){
    short8 a[2], b[2];
#pragma unroll
    for (int js = 0; js < 2; ++js)
      a[js] = *(const short8*)(W + (size_t)(j0 + js*16 + low)*C_ + kc*32 + quad*8);
#pragma unroll
    for (int ls = 0; ls < 2; ++ls)
      b[ls] = *(const short8*)(Xn + (size_t)(l0 + ls*16 + low)*C_ + kc*32 + quad*8);
#pragma unroll
    for (int js = 0; js < 2; ++js)
#pragma unroll
      for (int ls = 0; ls < 2; ++ls)
        acc[js][ls] = mfma16(a[js], b[ls], acc[js][ls]);
  }
#pragma unroll
  for (int js = 0; js < 2; ++js){
    f32x4 bb = *(const f32x4*)(bias + j0 + js*16 + quad*4);
#pragma unroll
    for (int ls = 0; ls < 2; ++ls){
      int l = l0 + ls*16 + low;
      if (!isK){
#pragma unroll
        for (int r = 0; r < 4; ++r){
          int c = j0 + js*16 + quad*4 + r;        // output channel
          outp[VP_OFF(n, c, l)] = f2bf(acc[js][ls][r] + bb[r]);
        }
      } else {
        union { ushort u[4]; uint2v v; } pk;
#pragma unroll
        for (int r = 0; r < 4; ++r) pk.u[r] = f2bf(acc[js][ls][r] + bb[r]);
        *(uint2v*)(outp + ((size_t)n*L_ + l)*CK_ + j0 + js*16 + quad*4) = pk.v;
      }
    }
  }
}

// ---------- stats: partial row/col sums of exp(cor) ----------
__global__ __launch_bounds__(256) void stats_kernel(
    const ushort* __restrict__ k1t, const ushort* __restrict__ k2t,
    float* __restrict__ S1part, float* __restrict__ S2part){
  int n = blockIdx.z;
  int m0 = blockIdx.x * 128, l0 = blockIdx.y * 128;
  int t = threadIdx.x, w = t >> 6, lane = t & 63, quad = lane >> 4, low = lane & 15;
  __shared__ float rowsum[128];
  __shared__ float colsum[4][128];
  const ushort* ka = k1t + (size_t)n * L_ * CK_;
  const ushort* kb = k2t + (size_t)n * L_ * CK_;
  short8 a[2], b[8];
#pragma unroll
  for (int lt = 0; lt < 2; ++lt)
    a[lt] = *(const short8*)(ka + (size_t)(l0 + w*32 + lt*16 + low)*CK_ + quad*8);
#pragma unroll
  for (int mt = 0; mt < 8; ++mt)
    b[mt] = *(const short8*)(kb + (size_t)(m0 + mt*16 + low)*CK_ + quad*8);
  float rp[2][4] = {}; float cp[8] = {};
  const f32x4 zero = {0.f, 0.f, 0.f, 0.f};
#pragma unroll
  for (int lt = 0; lt < 2; ++lt)
#pragma unroll
    for (int mt = 0; mt < 8; ++mt){
      f32x4 e = mfma16(a[lt], b[mt], zero);
#pragma unroll
      for (int r = 0; r < 4; ++r){
        float v = __builtin_amdgcn_exp2f(e[r] * 1.44269504088896f);
        rp[lt][r] += v;
        cp[mt] += v;
      }
    }
#pragma unroll
  for (int lt = 0; lt < 2; ++lt)
#pragma unroll
    for (int r = 0; r < 4; ++r){
      float v = rp[lt][r];
      v += __shfl_xor(v, 1); v += __shfl_xor(v, 2);
      v += __shfl_xor(v, 4); v += __shfl_xor(v, 8);
      if (low == 0) rowsum[w*32 + lt*16 + quad*4 + r] = v;
    }
#pragma unroll
  for (int mt = 0; mt < 8; ++mt){
    float v = cp[mt];
    v += __shfl_xor(v, 16); v += __shfl_xor(v, 32);
    if (quad == 0) colsum[w][mt*16 + low] = v;
  }
  __syncthreads();
  if (t < 128)
    S1part[((size_t)n*32 + blockIdx.x)*L_ + l0 + t] = rowsum[t];
  else {
    int m = t - 128;
    S2part[((size_t)n*32 + blockIdx.y)*L_ + m0 + m] =
        colsum[0][m] + colsum[1][m] + colsum[2][m] + colsum[3][m];
  }
}

// ---------- reduce partials -> lsv = log2(1/S) = -log2(S) ----------
__global__ __launch_bounds__(256) void reduce_inv_kernel(
    const float* __restrict__ S1part, const float* __restrict__ S2part,
    float* __restrict__ invS1, float* __restrict__ invS2){
  int idx = blockIdx.x * 256 + threadIdx.x;          // 0..16383
  int which = idx >> 13;
  int r = idx & 8191;                                // n*L + l
  int n = r >> 12, l = r & 4095;
  const float* P = which ? S2part : S1part;
  float s = 0.f;
#pragma unroll
  for (int j = 0; j < 32; ++j) s += P[((size_t)n*32 + j)*L_ + l];
  (which ? invS2 : invS1)[(size_t)n*L_ + l] = -__builtin_amdgcn_logf(s);
}

#define LOG2E_ 1.44269504088896f

// ---------- unified flash r-kernel v8: v7 + qs-interleaved e->PV + setprio.
// Diagnosis after v7 (57.6 us): MfmaUtil 29%, VALUBusy 31%, no barriers, no
// main-loop LDS, FETCH at compulsory level -> ~40% of cycles neither pipe
// issues. 2 waves/SIMD (register-locked: 128 acc + ~108 arch) run the same
// schedule and phase-lock: both in the exp chain, then both in the PV burst,
// contending for one pipe while the other idles.
// Fix (no new registers): (1) interleave at qs granularity — PV's qs-column
// (8 MFMAs) only needs pb[qs], so the loop becomes 4x {2 e-MFMA -> 8 exp+pack
// -> 8 PV MFMA}, alternating VALU/MFMA bursts within each wave; (2) T5
// s_setprio(1) around each PV burst so the CU scheduler staggers the two
// waves into complementary phases; (3) kA/sv prefetch sits in qs=3's e-MFMA
// latency shadow.
__global__ __launch_bounds__(256, 2) void cross_attn_r_kernel(
    const ushort* __restrict__ k1t, const ushort* __restrict__ k2t,
    const ushort* __restrict__ v1,  const ushort* __restrict__ v2,
    const float* __restrict__ invS1, const float* __restrict__ invS2,
    const float* __restrict__ x1, const float* __restrict__ x2,
    float* __restrict__ out){
  int bid = blockIdx.x;
  int slice = bid & 7;                 // -> XCD (bid % 8 round-robin)
  int qb = bid >> 3;                   // 0..63
  int n = slice & 1;
  int which = (slice >> 1) & 1;
  int chalf = slice >> 2;
  const ushort* kA = which ? k2t : k1t;
  const ushort* kB = which ? k1t : k2t;
  const ushort* V  = which ? v2  : v1;
  const float* iS  = which ? invS2 : invS1;
  const float* X   = which ? x2 : x1;
  float* O = out + (size_t)which * N_ * C_ * L_;
  int q0 = qb * 64, c0 = chalf * 128;
  int t = threadIdx.x, w = t >> 6, lane = t & 63, quad = lane >> 4, low = lane & 15;
  __shared__ __align__(16) float red[4][16][68];   // [wave][c_local][q(+pad)]
  const ushort* kAn = kA + (size_t)n * L_ * CK_;
  const ushort* kBn = kB + (size_t)n * L_ * CK_;
  const float*  iSn = iS + (size_t)n * L_;

  // permuted-row A base: A-row m=low -> kA row (m>>2)*8 + (m&3)
  const ushort* kA_base = kAn + (size_t)((low >> 2) * 8 + (low & 3)) * CK_ + quad * 8;
  const float*  sv_base = iSn + quad * 8;
  // packed-V lane base: tiles for this (n, chalf) start at cblk = chalf*8
  const ushort* Vp_lane = V + ((size_t)n * 128 * 16 + chalf * 8) * 512 + (size_t)lane * 8;

  // E-phase B operand (q rows of kB) is loop-invariant: preload once.
  short8 be[4];
#pragma unroll
  for (int qs = 0; qs < 4; ++qs)
    be[qs] = *(const short8*)(kBn + (size_t)(q0 + qs*16 + low) * CK_ + quad * 8);

  f32x4 acc[8][4] = {};
  const f32x4 zero = {0.f, 0.f, 0.f, 0.f};

  // software-pipelined kA-row + scale loads (16 VGPR)
  int pfirst = w * 32;
  short8 a0 = *(const short8*)(kA_base + (size_t)pfirst * CK_);
  short8 a1 = *(const short8*)(kA_base + (size_t)(pfirst + 4) * CK_);
  f32x4 sv0 = *(const f32x4*)(sv_base + pfirst);
  f32x4 sv1 = *(const f32x4*)(sv_base + pfirst + 4);

  for (int kk = 0; kk < L_ / 128; ++kk){
    // V for this iteration: 8 consecutive 1 KB tiles (pblk = kk*4 + w)
    const ushort* vt = Vp_lane + (size_t)(kk*4 + w) * 16 * 512;
    short8 vv[8];
#pragma unroll
    for (int ct = 0; ct < 8; ++ct)
      vv[ct] = *(const short8*)(vt + ct * 512);
    int pn = ((kk + 1) & 31) * 128 + w * 32;   // next-iter kA offset (wraps; harmless)

    // qs-interleaved e->PV: per qs, VALU burst (exp/pack) then MFMA burst (PV)
#pragma unroll
    for (int qs = 0; qs < 4; ++qs){
      f32x4 e0 = mfma16(a0, be[qs], zero);   // rows p+quad*8+r
      f32x4 e1 = mfma16(a1, be[qs], zero);   // rows p+quad*8+4+r
      float p0 = __builtin_amdgcn_exp2f(__fmaf_rn(e0[0], LOG2E_, sv0[0]));
      float p1 = __builtin_amdgcn_exp2f(__fmaf_rn(e0[1], LOG2E_, sv0[1]));
      float p2 = __builtin_amdgcn_exp2f(__fmaf_rn(e0[2], LOG2E_, sv0[2]));
      float p3 = __builtin_amdgcn_exp2f(__fmaf_rn(e0[3], LOG2E_, sv0[3]));
      float p4 = __builtin_amdgcn_exp2f(__fmaf_rn(e1[0], LOG2E_, sv1[0]));
      float p5 = __builtin_amdgcn_exp2f(__fmaf_rn(e1[1], LOG2E_, sv1[1]));
      float p6 = __builtin_amdgcn_exp2f(__fmaf_rn(e1[2], LOG2E_, sv1[2]));
      float p7 = __builtin_amdgcn_exp2f(__fmaf_rn(e1[3], LOG2E_, sv1[3]));
      union { __hip_bfloat162 h[4]; short8 v; } pk;
      pk.h[0] = __float22bfloat162_rn(make_float2(p0, p1));
      pk.h[1] = __float22bfloat162_rn(make_float2(p2, p3));
      pk.h[2] = __float22bfloat162_rn(make_float2(p4, p5));
      pk.h[3] = __float22bfloat162_rn(make_float2(p6, p7));
      short8 pb = pk.v;
      if (qs == 3){
        // a0/a1 dead after this qs's e-MFMAs: prefetch next iter in their
        // latency shadow (sv still live until the exps above — done now).
        a0 = *(const short8*)(kA_base + (size_t)pn * CK_);
        a1 = *(const short8*)(kA_base + (size_t)(pn + 4) * CK_);
        sv0 = *(const f32x4*)(sv_base + pn);
        sv1 = *(const f32x4*)(sv_base + pn + 4);
      }
      __builtin_amdgcn_s_setprio(1);
#pragma unroll
      for (int ct = 0; ct < 8; ++ct)
        acc[ct][qs] = mfma16(vv[ct], pb, acc[ct][qs]);
      __builtin_amdgcn_s_setprio(0);
    }
  }

  // --- epilogue: cross-wave reduction of the 4 disjoint-p partials + x add
  int cl = t >> 4, qg = (t & 15) * 4;
#pragma unroll
  for (int ct = 0; ct < 8; ++ct){
#pragma unroll
    for (int qs = 0; qs < 4; ++qs)
#pragma unroll
      for (int r = 0; r < 4; ++r)
        red[w][quad*4 + r][qs*16 + low] = acc[ct][qs][r];
    __syncthreads();
    f32x4 s0 = *(const f32x4*)&red[0][cl][qg];
    f32x4 s1 = *(const f32x4*)&red[1][cl][qg];
    f32x4 s2 = *(const f32x4*)&red[2][cl][qg];
    f32x4 s3 = *(const f32x4*)&red[3][cl][qg];
    f32x4 s = (s0 + s1) + (s2 + s3);
    size_t idx = ((size_t)n * C_ + c0 + ct*16 + cl) * L_ + q0 + qg;
    const float4 xv = *(const float4*)(X + idx);
    float4 o = make_float4(xv.x + s[0], xv.y + s[1], xv.z + s[2], xv.w + s[3]);
    *(float4*)(O + idx) = o;
    __syncthreads();
  }
}

extern "C" void kernel_launch(void* const* d_in, const int* in_sizes, int n_in,
                              void* d_out, int out_size, void* d_ws, size_t ws_size,
                              hipStream_t stream) {
  const float* x1  = (const float*)d_in[0];
  const float* x2  = (const float*)d_in[1];
  const float* Wk1 = (const float*)d_in[2];
  const float* bk1 = (const float*)d_in[3];
  const float* Wk2 = (const float*)d_in[4];
  const float* bk2 = (const float*)d_in[5];
  const float* Wv1 = (const float*)d_in[6];
  const float* bv1 = (const float*)d_in[7];
  const float* Wv2 = (const float*)d_in[8];
  const float* bv2 = (const float*)d_in[9];

  char* ws = (char*)d_ws;
  size_t off = 0;
  auto carve = [&](size_t bytes) -> void* {
    void* p = ws + off; off += (bytes + 255) & ~(size_t)255; return p;
  };
  ushort* xT1   = (ushort*)carve((size_t)N_*L_*C_*2);
  ushort* xT2   = (ushort*)carve((size_t)N_*L_*C_*2);
  ushort* Wk1b  = (ushort*)carve((size_t)CK_*C_*2);
  ushort* Wk2b  = (ushort*)carve((size_t)CK_*C_*2);
  ushort* Wv1b  = (ushort*)carve((size_t)C_*C_*2);
  ushort* Wv2b  = (ushort*)carve((size_t)C_*C_*2);
  ushort* k1t   = (ushort*)carve((size_t)N_*L_*CK_*2);
  ushort* k2t   = (ushort*)carve((size_t)N_*L_*CK_*2);
  ushort* v1    = (ushort*)carve((size_t)N_*C_*L_*2);
  ushort* v2    = (ushort*)carve((size_t)N_*C_*L_*2);
  float*  S1p   = (float*)carve((size_t)N_*32*L_*4);
  float*  S2p   = (float*)carve((size_t)N_*32*L_*4);
  float*  invS1 = (float*)carve((size_t)N_*L_*4);
  float*  invS2 = (float*)carve((size_t)N_*L_*4);

  convert_x_kernel<<<dim3(L_/64, C_/128, 4), 256, 0, stream>>>(x1, x2, xT1, xT2);
  convert_w_kernel<<<dim3((2*CK_*C_ + 2*C_*C_) / 256), 256, 0, stream>>>(
      Wk1, Wk2, Wv1, Wv2, Wk1b, Wk2b, Wv1b, Wv2b);
  proj_kernel<<<dim3(L_/128, 18, N_), 256, 0, stream>>>(
      xT1, xT2, Wk1b, Wk2b, Wv1b, Wv2b, bk1, bk2, bv1, bv2, k1t, k2t, v1, v2);
  stats_kernel<<<dim3(L_/128, L_/128, N_), 256, 0, stream>>>(k1t, k2t, S1p, S2p);
  reduce_inv_kernel<<<dim3(2*N_*L_/256), 256, 0, stream>>>(S1p, S2p, invS1, invS2);
  cross_attn_r_kernel<<<dim3(2 * N_ * (C_/128) * (L_/64), 1, 1), 256, 0, stream>>>(
      k1t, k2t, v1, v2, invS1, invS2, x1, x2, (float*)d_out);
}

// Round 6
// 165.742 us; speedup vs baseline: 1.2057x; 1.0380x over previous
//
#include <hip/hip_runtime.h>
#include <hip/hip_bf16.h>

#define N_  2
#define C_  256
#define CK_ 32
#define L_  4096

typedef __attribute__((ext_vector_type(8))) short short8;   // 8 bf16 (4 VGPRs)
typedef __attribute__((ext_vector_type(4))) float f32x4;    // MFMA C/D
typedef __attribute__((ext_vector_type(2))) unsigned int uint2v;
typedef unsigned short ushort;

__device__ __forceinline__ ushort f2bf(float f){
  unsigned u = __float_as_uint(f);
  u += 0x7fffu + ((u >> 16) & 1u);     // RNE
  return (ushort)(u >> 16);
}

__device__ __forceinline__ f32x4 mfma16(short8 a, short8 b, f32x4 c){
  return __builtin_amdgcn_mfma_f32_16x16x32_bf16(a, b, c, 0, 0, 0);
}

// ---------- fused convert: x transpose->bf16 + weights->bf16 ----------
// Old convert_x read f32 in 256 B segments at 16 KB stride (L*4B) — the same
// channel-aliasing pathology the v7 packed-V fix removed (64 B @ 8 KB).
// New geometry: 256l x 32c tile; each c-row is ONE contiguous 1 KB wave read.
// LDS f32 [c][l] tile: b128 row writes (conflict-free), scalar column reads
// (~4-way, hidden under memory). Writes go out as 64 B runs (full lines).
// Weight conversion fused as grid tail (saves a launch).
__global__ __launch_bounds__(256) void convert_xw_kernel(
    const float* __restrict__ x1, const float* __restrict__ x2,
    ushort* __restrict__ xT1, ushort* __restrict__ xT2,
    const float* __restrict__ Wk1, const float* __restrict__ Wk2,
    const float* __restrict__ Wv1, const float* __restrict__ Wv2,
    ushort* __restrict__ o1, ushort* __restrict__ o2,
    ushort* __restrict__ o3, ushort* __restrict__ o4){
  int b = blockIdx.x, t = threadIdx.x;
  if (b >= 512){                       // ---- weight tail
    int idx = (b - 512) * 256 + t;
    const int KS = CK_ * C_;           // 8192
    const int VS = C_ * C_;            // 65536
    if (idx < KS)                 o1[idx] = f2bf(Wk1[idx]);
    else if (idx < 2*KS)          o2[idx - KS] = f2bf(Wk2[idx - KS]);
    else if (idx < 2*KS + VS)     o3[idx - 2*KS] = f2bf(Wv1[idx - 2*KS]);
    else if (idx < 2*KS + 2*VS)   o4[idx - 2*KS - VS] = f2bf(Wv2[idx - 2*KS - VS]);
    return;
  }
  __shared__ float tt[32][264];        // [c][l], 33.8 KB, row 1056 B (16-aligned)
  int z = b & 3; int n = z & 1;
  const float* x = (z >> 1) ? x2 : x1;
  ushort* xT = (z >> 1) ? xT2 : xT1;
  int tile = b >> 2;                   // 0..127
  int l0 = (tile & 15) * 256, c0 = (tile >> 4) * 32;
  int w = t >> 6, lam = t & 63;
  const float* xs = x + (size_t)n * C_ * L_;
  ushort* xd = xT + (size_t)n * L_ * C_;
  // phase 1: 32 c-rows, each read as a contiguous 1 KB wave load
#pragma unroll
  for (int k = 0; k < 8; ++k){
    int cr = w * 8 + k;
    float4 f = *(const float4*)(xs + (size_t)(c0 + cr) * L_ + l0 + lam * 4);
    *(float4*)&tt[cr][lam * 4] = f;
  }
  __syncthreads();
  // phase 2: column-gather 8 c's per thread, pack short8, 64 B write runs
  int g = t & 3, lr = t >> 2;          // g: c-group, lr: 0..63
#pragma unroll
  for (int k = 0; k < 4; ++k){
    int l = k * 64 + lr;
    union { __hip_bfloat162 h[4]; short8 v; } pk;
#pragma unroll
    for (int j = 0; j < 4; ++j)
      pk.h[j] = __float22bfloat162_rn(
          make_float2(tt[g*8 + 2*j][l], tt[g*8 + 2*j + 1][l]));
    *(short8*)(xd + (size_t)(l0 + l) * C_ + c0 + g * 8) = pk.v;
  }
}

// V packed layout: per n, 128 pblk (32 p-cols) x 16 cblk (16 c-rows) tiles of
// 512 elts (1 KB). In-tile: elt (c,p) at quad*128 + (c&15)*8 + (p&7), where
// quad = (p&31)>>3. A wave-load of short8 at tile_base + lane*8 (lane =
// quad*16+row) is fully contiguous 1 KB and delivers exactly the PV MFMA
// A-fragment: lane(quad,low) <- V[cblk*16+low][pblk*32 + quad*8 + j].
#define VP_OFF(nn, cc, pp) \
  ((((size_t)(nn)*128 + ((pp)>>5))*16 + ((cc)>>4))*512 + \
   (((pp)&31)>>3)*128 + ((cc)&15)*8 + ((pp)&7))

// ---------- fused projections: k1t/k2t [n][L][CK], v1/v2 packed tiles ----------
__global__ __launch_bounds__(256) void proj_kernel(
    const ushort* __restrict__ xT1, const ushort* __restrict__ xT2,
    const ushort* __restrict__ Wk1b, const ushort* __restrict__ Wk2b,
    const ushort* __restrict__ Wv1b, const ushort* __restrict__ Wv2b,
    const float* __restrict__ bk1, const float* __restrict__ bk2,
    const float* __restrict__ bv1, const float* __restrict__ bv2,
    ushort* __restrict__ k1t, ushort* __restrict__ k2t,
    ushort* __restrict__ v1,  ushort* __restrict__ v2){
  int y = blockIdx.y, n = blockIdx.z;
  int t = threadIdx.x, w = t >> 6, lane = t & 63, quad = lane >> 4, low = lane & 15;
  const ushort* X; const ushort* W; const float* bias; ushort* outp; int jt; bool isK;
  if (y < 8)       { X = xT1; W = Wv1b; bias = bv1; outp = v1;  jt = y;     isK = false; }
  else if (y < 16) { X = xT2; W = Wv2b; bias = bv2; outp = v2;  jt = y - 8; isK = false; }
  else if (y == 16){ X = xT1; W = Wk1b; bias = bk1; outp = k1t; jt = 0;     isK = true; }
  else             { X = xT2; W = Wk2b; bias = bk2; outp = k2t; jt = 0;     isK = true; }
  int j0 = jt * 32;
  int l0 = blockIdx.x * 128 + w * 32;
  const ushort* Xn = X + (size_t)n * L_ * C_;
  f32x4 acc[2][2] = {};
#pragma unroll
  for (int kc = 0; kc < 8; ++kc){
    short8 a[2], b[2];
#pragma unroll
    for (int js = 0; js < 2; ++js)
      a[js] = *(const short8*)(W + (size_t)(j0 + js*16 + low)*C_ + kc*32 + quad*8);
#pragma unroll
    for (int ls = 0; ls < 2; ++ls)
      b[ls] = *(const short8*)(Xn + (size_t)(l0 + ls*16 + low)*C_ + kc*32 + quad*8);
#pragma unroll
    for (int js = 0; js < 2; ++js)
#pragma unroll
      for (int ls = 0; ls < 2; ++ls)
        acc[js][ls] = mfma16(a[js], b[ls], acc[js][ls]);
  }
#pragma unroll
  for (int js = 0; js < 2; ++js){
    f32x4 bb = *(const f32x4*)(bias + j0 + js*16 + quad*4);
#pragma unroll
    for (int ls = 0; ls < 2; ++ls){
      int l = l0 + ls*16 + low;
      if (!isK){
#pragma unroll
        for (int r = 0; r < 4; ++r){
          int c = j0 + js*16 + quad*4 + r;        // output channel
          outp[VP_OFF(n, c, l)] = f2bf(acc[js][ls][r] + bb[r]);
        }
      } else {
        union { ushort u[4]; uint2v v; } pk;
#pragma unroll
        for (int r = 0; r < 4; ++r) pk.u[r] = f2bf(acc[js][ls][r] + bb[r]);
        *(uint2v*)(outp + ((size_t)n*L_ + l)*CK_ + j0 + js*16 + quad*4) = pk.v;
      }
    }
  }
}

// ---------- stats: partial row/col sums of exp(cor) ----------
__global__ __launch_bounds__(256) void stats_kernel(
    const ushort* __restrict__ k1t, const ushort* __restrict__ k2t,
    float* __restrict__ S1part, float* __restrict__ S2part){
  int n = blockIdx.z;
  int m0 = blockIdx.x * 128, l0 = blockIdx.y * 128;
  int t = threadIdx.x, w = t >> 6, lane = t & 63, quad = lane >> 4, low = lane & 15;
  __shared__ float rowsum[128];
  __shared__ float colsum[4][128];
  const ushort* ka = k1t + (size_t)n * L_ * CK_;
  const ushort* kb = k2t + (size_t)n * L_ * CK_;
  short8 a[2], b[8];
#pragma unroll
  for (int lt = 0; lt < 2; ++lt)
    a[lt] = *(const short8*)(ka + (size_t)(l0 + w*32 + lt*16 + low)*CK_ + quad*8);
#pragma unroll
  for (int mt = 0; mt < 8; ++mt)
    b[mt] = *(const short8*)(kb + (size_t)(m0 + mt*16 + low)*CK_ + quad*8);
  float rp[2][4] = {}; float cp[8] = {};
  const f32x4 zero = {0.f, 0.f, 0.f, 0.f};
#pragma unroll
  for (int lt = 0; lt < 2; ++lt)
#pragma unroll
    for (int mt = 0; mt < 8; ++mt){
      f32x4 e = mfma16(a[lt], b[mt], zero);
#pragma unroll
      for (int r = 0; r < 4; ++r){
        float v = __builtin_amdgcn_exp2f(e[r] * 1.44269504088896f);
        rp[lt][r] += v;
        cp[mt] += v;
      }
    }
#pragma unroll
  for (int lt = 0; lt < 2; ++lt)
#pragma unroll
    for (int r = 0; r < 4; ++r){
      float v = rp[lt][r];
      v += __shfl_xor(v, 1); v += __shfl_xor(v, 2);
      v += __shfl_xor(v, 4); v += __shfl_xor(v, 8);
      if (low == 0) rowsum[w*32 + lt*16 + quad*4 + r] = v;
    }
#pragma unroll
  for (int mt = 0; mt < 8; ++mt){
    float v = cp[mt];
    v += __shfl_xor(v, 16); v += __shfl_xor(v, 32);
    if (quad == 0) colsum[w][mt*16 + low] = v;
  }
  __syncthreads();
  if (t < 128)
    S1part[((size_t)n*32 + blockIdx.x)*L_ + l0 + t] = rowsum[t];
  else {
    int m = t - 128;
    S2part[((size_t)n*32 + blockIdx.y)*L_ + m0 + m] =
        colsum[0][m] + colsum[1][m] + colsum[2][m] + colsum[3][m];
  }
}

// ---------- reduce partials -> lsv = log2(1/S) = -log2(S) ----------
__global__ __launch_bounds__(256) void reduce_inv_kernel(
    const float* __restrict__ S1part, const float* __restrict__ S2part,
    float* __restrict__ invS1, float* __restrict__ invS2){
  int idx = blockIdx.x * 256 + threadIdx.x;          // 0..16383
  int which = idx >> 13;
  int r = idx & 8191;                                // n*L + l
  int n = r >> 12, l = r & 4095;
  const float* P = which ? S2part : S1part;
  float s = 0.f;
#pragma unroll
  for (int j = 0; j < 32; ++j) s += P[((size_t)n*32 + j)*L_ + l];
  (which ? invS2 : invS1)[(size_t)n*L_ + l] = -__builtin_amdgcn_logf(s);
}

#define LOG2E_ 1.44269504088896f

// ---------- unified flash r-kernel v8 (frozen from Round 5, 49.9 us):
// in-register P via permuted-row A loads, packed-V 1 KB tile loads,
// XCD-aware flat grid, qs-interleaved e->PV with setprio staggering.
__global__ __launch_bounds__(256, 2) void cross_attn_r_kernel(
    const ushort* __restrict__ k1t, const ushort* __restrict__ k2t,
    const ushort* __restrict__ v1,  const ushort* __restrict__ v2,
    const float* __restrict__ invS1, const float* __restrict__ invS2,
    const float* __restrict__ x1, const float* __restrict__ x2,
    float* __restrict__ out){
  int bid = blockIdx.x;
  int slice = bid & 7;                 // -> XCD (bid % 8 round-robin)
  int qb = bid >> 3;                   // 0..63
  int n = slice & 1;
  int which = (slice >> 1) & 1;
  int chalf = slice >> 2;
  const ushort* kA = which ? k2t : k1t;
  const ushort* kB = which ? k1t : k2t;
  const ushort* V  = which ? v2  : v1;
  const float* iS  = which ? invS2 : invS1;
  const float* X   = which ? x2 : x1;
  float* O = out + (size_t)which * N_ * C_ * L_;
  int q0 = qb * 64, c0 = chalf * 128;
  int t = threadIdx.x, w = t >> 6, lane = t & 63, quad = lane >> 4, low = lane & 15;
  __shared__ __align__(16) float red[4][16][68];   // [wave][c_local][q(+pad)]
  const ushort* kAn = kA + (size_t)n * L_ * CK_;
  const ushort* kBn = kB + (size_t)n * L_ * CK_;
  const float*  iSn = iS + (size_t)n * L_;

  // permuted-row A base: A-row m=low -> kA row (m>>2)*8 + (m&3)
  const ushort* kA_base = kAn + (size_t)((low >> 2) * 8 + (low & 3)) * CK_ + quad * 8;
  const float*  sv_base = iSn + quad * 8;
  // packed-V lane base: tiles for this (n, chalf) start at cblk = chalf*8
  const ushort* Vp_lane = V + ((size_t)n * 128 * 16 + chalf * 8) * 512 + (size_t)lane * 8;

  // E-phase B operand (q rows of kB) is loop-invariant: preload once.
  short8 be[4];
#pragma unroll
  for (int qs = 0; qs < 4; ++qs)
    be[qs] = *(const short8*)(kBn + (size_t)(q0 + qs*16 + low) * CK_ + quad * 8);

  f32x4 acc[8][4] = {};
  const f32x4 zero = {0.f, 0.f, 0.f, 0.f};

  // software-pipelined kA-row + scale loads (16 VGPR)
  int pfirst = w * 32;
  short8 a0 = *(const short8*)(kA_base + (size_t)pfirst * CK_);
  short8 a1 = *(const short8*)(kA_base + (size_t)(pfirst + 4) * CK_);
  f32x4 sv0 = *(const f32x4*)(sv_base + pfirst);
  f32x4 sv1 = *(const f32x4*)(sv_base + pfirst + 4);

  for (int kk = 0; kk < L_ / 128; ++kk){
    // V for this iteration: 8 consecutive 1 KB tiles (pblk = kk*4 + w)
    const ushort* vt = Vp_lane + (size_t)(kk*4 + w) * 16 * 512;
    short8 vv[8];
#pragma unroll
    for (int ct = 0; ct < 8; ++ct)
      vv[ct] = *(const short8*)(vt + ct * 512);
    int pn = ((kk + 1) & 31) * 128 + w * 32;   // next-iter kA offset (wraps; harmless)

    // qs-interleaved e->PV: per qs, VALU burst (exp/pack) then MFMA burst (PV)
#pragma unroll
    for (int qs = 0; qs < 4; ++qs){
      f32x4 e0 = mfma16(a0, be[qs], zero);   // rows p+quad*8+r
      f32x4 e1 = mfma16(a1, be[qs], zero);   // rows p+quad*8+4+r
      float p0 = __builtin_amdgcn_exp2f(__fmaf_rn(e0[0], LOG2E_, sv0[0]));
      float p1 = __builtin_amdgcn_exp2f(__fmaf_rn(e0[1], LOG2E_, sv0[1]));
      float p2 = __builtin_amdgcn_exp2f(__fmaf_rn(e0[2], LOG2E_, sv0[2]));
      float p3 = __builtin_amdgcn_exp2f(__fmaf_rn(e0[3], LOG2E_, sv0[3]));
      float p4 = __builtin_amdgcn_exp2f(__fmaf_rn(e1[0], LOG2E_, sv1[0]));
      float p5 = __builtin_amdgcn_exp2f(__fmaf_rn(e1[1], LOG2E_, sv1[1]));
      float p6 = __builtin_amdgcn_exp2f(__fmaf_rn(e1[2], LOG2E_, sv1[2]));
      float p7 = __builtin_amdgcn_exp2f(__fmaf_rn(e1[3], LOG2E_, sv1[3]));
      union { __hip_bfloat162 h[4]; short8 v; } pk;
      pk.h[0] = __float22bfloat162_rn(make_float2(p0, p1));
      pk.h[1] = __float22bfloat162_rn(make_float2(p2, p3));
      pk.h[2] = __float22bfloat162_rn(make_float2(p4, p5));
      pk.h[3] = __float22bfloat162_rn(make_float2(p6, p7));
      short8 pb = pk.v;
      if (qs == 3){
        // a0/a1 dead after this qs's e-MFMAs: prefetch next iter in their
        // latency shadow (sv consumed by the exps above — done now).
        a0 = *(const short8*)(kA_base + (size_t)pn * CK_);
        a1 = *(const short8*)(kA_base + (size_t)(pn + 4) * CK_);
        sv0 = *(const f32x4*)(sv_base + pn);
        sv1 = *(const f32x4*)(sv_base + pn + 4);
      }
      __builtin_amdgcn_s_setprio(1);
#pragma unroll
      for (int ct = 0; ct < 8; ++ct)
        acc[ct][qs] = mfma16(vv[ct], pb, acc[ct][qs]);
      __builtin_amdgcn_s_setprio(0);
    }
  }

  // --- epilogue: cross-wave reduction of the 4 disjoint-p partials + x add
  int cl = t >> 4, qg = (t & 15) * 4;
#pragma unroll
  for (int ct = 0; ct < 8; ++ct){
#pragma unroll
    for (int qs = 0; qs < 4; ++qs)
#pragma unroll
      for (int r = 0; r < 4; ++r)
        red[w][quad*4 + r][qs*16 + low] = acc[ct][qs][r];
    __syncthreads();
    f32x4 s0 = *(const f32x4*)&red[0][cl][qg];
    f32x4 s1 = *(const f32x4*)&red[1][cl][qg];
    f32x4 s2 = *(const f32x4*)&red[2][cl][qg];
    f32x4 s3 = *(const f32x4*)&red[3][cl][qg];
    f32x4 s = (s0 + s1) + (s2 + s3);
    size_t idx = ((size_t)n * C_ + c0 + ct*16 + cl) * L_ + q0 + qg;
    const float4 xv = *(const float4*)(X + idx);
    float4 o = make_float4(xv.x + s[0], xv.y + s[1], xv.z + s[2], xv.w + s[3]);
    *(float4*)(O + idx) = o;
    __syncthreads();
  }
}

extern "C" void kernel_launch(void* const* d_in, const int* in_sizes, int n_in,
                              void* d_out, int out_size, void* d_ws, size_t ws_size,
                              hipStream_t stream) {
  const float* x1  = (const float*)d_in[0];
  const float* x2  = (const float*)d_in[1];
  const float* Wk1 = (const float*)d_in[2];
  const float* bk1 = (const float*)d_in[3];
  const float* Wk2 = (const float*)d_in[4];
  const float* bk2 = (const float*)d_in[5];
  const float* Wv1 = (const float*)d_in[6];
  const float* bv1 = (const float*)d_in[7];
  const float* Wv2 = (const float*)d_in[8];
  const float* bv2 = (const float*)d_in[9];

  char* ws = (char*)d_ws;
  size_t off = 0;
  auto carve = [&](size_t bytes) -> void* {
    void* p = ws + off; off += (bytes + 255) & ~(size_t)255; return p;
  };
  ushort* xT1   = (ushort*)carve((size_t)N_*L_*C_*2);
  ushort* xT2   = (ushort*)carve((size_t)N_*L_*C_*2);
  ushort* Wk1b  = (ushort*)carve((size_t)CK_*C_*2);
  ushort* Wk2b  = (ushort*)carve((size_t)CK_*C_*2);
  ushort* Wv1b  = (ushort*)carve((size_t)C_*C_*2);
  ushort* Wv2b  = (ushort*)carve((size_t)C_*C_*2);
  ushort* k1t   = (ushort*)carve((size_t)N_*L_*CK_*2);
  ushort* k2t   = (ushort*)carve((size_t)N_*L_*CK_*2);
  ushort* v1    = (ushort*)carve((size_t)N_*C_*L_*2);
  ushort* v2    = (ushort*)carve((size_t)N_*C_*L_*2);
  float*  S1p   = (float*)carve((size_t)N_*32*L_*4);
  float*  S2p   = (float*)carve((size_t)N_*32*L_*4);
  float*  invS1 = (float*)carve((size_t)N_*L_*4);
  float*  invS2 = (float*)carve((size_t)N_*L_*4);

  // 512 x-transpose blocks + 576 weight blocks
  convert_xw_kernel<<<dim3(512 + (2*CK_*C_ + 2*C_*C_) / 256), 256, 0, stream>>>(
      x1, x2, xT1, xT2, Wk1, Wk2, Wv1, Wv2, Wk1b, Wk2b, Wv1b, Wv2b);
  proj_kernel<<<dim3(L_/128, 18, N_), 256, 0, stream>>>(
      xT1, xT2, Wk1b, Wk2b, Wv1b, Wv2b, bk1, bk2, bv1, bv2, k1t, k2t, v1, v2);
  stats_kernel<<<dim3(L_/128, L_/128, N_), 256, 0, stream>>>(k1t, k2t, S1p, S2p);
  reduce_inv_kernel<<<dim3(2*N_*L_/256), 256, 0, stream>>>(S1p, S2p, invS1, invS2);
  cross_attn_r_kernel<<<dim3(2 * N_ * (C_/128) * (L_/64), 1, 1), 256, 0, stream>>>(
      k1t, k2t, v1, v2, invS1, invS2, x1, x2, (float*)d_out);
}